// Round 9
// baseline (749.081 us; speedup 1.0000x reference)
//
#include <hip/hip_runtime.h>

typedef unsigned short u16;
typedef __bf16 bf16x8 __attribute__((ext_vector_type(8)));
typedef float f32x4 __attribute__((ext_vector_type(4)));

__device__ __forceinline__ float bf2f(u16 u){ union{unsigned i;float f;}x; x.i=((unsigned)u)<<16; return x.f; }
__device__ __forceinline__ u16 f2bf(float f){ union{float f;unsigned i;}x; x.f=f; unsigned r = x.i + 0x7FFFu + ((x.i>>16)&1u); return (u16)(r>>16); }
__device__ __forceinline__ float sigm(float x){ return 1.f/(1.f+expf(-x)); }

struct __align__(8) U16x4 { u16 v[4]; };

#define PSTRIDE 8388608ull   // elems per split in partial buffer [4][8192][1024]

// ---------------- merged f32 [K][N] -> bf16 [N][K] transpose-convert ----------------
struct CJob { const float* src; u16* dst; int K, N, base; };
struct CJobs { CJob j[27]; };

__global__ void conv_all(CJobs cj){
  __shared__ u16 tile[128][65];
  int id = blockIdx.x;
  int sel = 0;
  #pragma unroll
  for (int i=1;i<27;++i) if (cj.j[i].base <= id) sel = i;
  const float* __restrict__ src = cj.j[sel].src;
  u16* __restrict__ dst = cj.j[sel].dst;
  int K = cj.j[sel].K, N = cj.j[sel].N;
  int lt = id - cj.j[sel].base;
  int tn = N >> 6;
  int k0 = (lt / tn) * 128, n0 = (lt % tn) * 64;
  int tid = threadIdx.x;
  #pragma unroll
  for (int it=0; it<8; ++it){
    int e = it*1024 + tid*4;
    int r = e>>6, c = e&63;
    float4 v = *(const float4*)(src + (size_t)(k0+r)*N + n0 + c);
    tile[r][c+0]=f2bf(v.x); tile[r][c+1]=f2bf(v.y); tile[r][c+2]=f2bf(v.z); tile[r][c+3]=f2bf(v.w);
  }
  __syncthreads();
  #pragma unroll
  for (int it=0; it<8; ++it){
    int e = it*1024 + tid*4;
    int n = e>>7, k = e&127;
    U16x4 o;
    #pragma unroll
    for (int j=0;j<4;++j) o.v[j] = tile[k+j][n];
    *(U16x4*)(dst + (size_t)(n0+n)*K + k0 + k) = o;
  }
}

// ---------------- LayerNorm: f32 [4096][1024] -> bf16 rows (stride ostride) ----------------
__global__ void ln_k(const float* __restrict__ x, const float* __restrict__ g, const float* __restrict__ b,
                     u16* __restrict__ out, int ostride){
  int row = blockIdx.x, tid = threadIdx.x;
  float4 v = *(const float4*)(x + (size_t)row*1024 + tid*4);
  float s = v.x+v.y+v.z+v.w;
  float ss = v.x*v.x+v.y*v.y+v.z*v.z+v.w*v.w;
  #pragma unroll
  for (int o=32;o;o>>=1){ s += __shfl_down(s,o); ss += __shfl_down(ss,o); }
  __shared__ float sm[8];
  int lane = tid&63, wv = tid>>6;
  if (!lane){ sm[wv]=s; sm[4+wv]=ss; }
  __syncthreads();
  s = sm[0]+sm[1]+sm[2]+sm[3]; ss = sm[4]+sm[5]+sm[6]+sm[7];
  float mean = s*(1.f/1024.f);
  float var = ss*(1.f/1024.f) - mean*mean;
  float inv = rsqrtf(var + 1e-5f);
  U16x4 o;
  const float* vp = &v.x;
  #pragma unroll
  for (int j=0;j<4;++j){
    int c = tid*4+j;
    o.v[j] = f2bf((vp[j]-mean)*inv*g[c] + b[c]);
  }
  *(U16x4*)(out + (size_t)row*ostride + tid*4) = o;
}

// ---------------- fused: out = x + p0 + p1 ; hcat[:, :1024] = LN(out) ----------------
__global__ void red_x_ln(const float* __restrict__ x, const u16* __restrict__ part,
                         const float* __restrict__ g, const float* __restrict__ b,
                         float* __restrict__ out, u16* __restrict__ hcat){
  int row = blockIdx.x, tid = threadIdx.x;
  size_t i = (size_t)row*1024 + tid*4;
  U16x4 p0 = *(const U16x4*)(part + i);
  U16x4 p1 = *(const U16x4*)(part + PSTRIDE + i);
  float4 xv = *(const float4*)(x + i);
  float4 v;
  v.x = xv.x + bf2f(p0.v[0]) + bf2f(p1.v[0]);
  v.y = xv.y + bf2f(p0.v[1]) + bf2f(p1.v[1]);
  v.z = xv.z + bf2f(p0.v[2]) + bf2f(p1.v[2]);
  v.w = xv.w + bf2f(p0.v[3]) + bf2f(p1.v[3]);
  *(float4*)(out + i) = v;
  float s = v.x+v.y+v.z+v.w;
  float ss = v.x*v.x+v.y*v.y+v.z*v.z+v.w*v.w;
  #pragma unroll
  for (int o=32;o;o>>=1){ s += __shfl_down(s,o); ss += __shfl_down(ss,o); }
  __shared__ float sm[8];
  int lane = tid&63, wv = tid>>6;
  if (!lane){ sm[wv]=s; sm[4+wv]=ss; }
  __syncthreads();
  s = sm[0]+sm[1]+sm[2]+sm[3]; ss = sm[4]+sm[5]+sm[6]+sm[7];
  float mean = s*(1.f/1024.f);
  float var = ss*(1.f/1024.f) - mean*mean;
  float inv = rsqrtf(var + 1e-5f);
  U16x4 o;
  const float* vp = &v.x;
  #pragma unroll
  for (int j=0;j<4;++j){
    int c = tid*4+j;
    o.v[j] = f2bf((vp[j]-mean)*inv*g[c] + b[c]);
  }
  *(U16x4*)(hcat + (size_t)row*2048 + tid*4) = o;
}

// ---------------- 3-phase chunked linear scan ----------------
__global__ void scan_p1(const u16* __restrict__ kbuf, const u16* __restrict__ vbuf,
                        const float* __restrict__ w_decay, float* __restrict__ carry){
  int c = blockIdx.x*256 + threadIdx.x;
  int chunk = blockIdx.y, b = blockIdx.z;
  float w = sigm(w_decay[c]);
  float s = 0.f;
  size_t idx = ((size_t)(b*2048 + chunk*64))*1024 + c;
  #pragma unroll 4
  for (int i=0;i<64;++i){ s = w*s + bf2f(kbuf[idx])*bf2f(vbuf[idx]); idx += 1024; }
  carry[((size_t)(b*32+chunk))*1024 + c] = s;
}
__global__ void scan_p2(const float* __restrict__ w_decay, const float* __restrict__ carry,
                        float* __restrict__ startv){
  int c = blockIdx.x*256 + threadIdx.x;
  int b = blockIdx.y;
  float w = sigm(w_decay[c]);
  float wL = w;
  #pragma unroll
  for (int i=0;i<6;++i) wL *= wL;   // w^64
  float p = 0.f;
  for (int j=0;j<32;++j){
    size_t id = ((size_t)(b*32+j))*1024 + c;
    startv[id] = p;
    p = wL*p + carry[id];
  }
}
__global__ void scan_p3(const u16* __restrict__ kbuf, const u16* __restrict__ vbuf, const u16* __restrict__ rbuf,
                        const float* __restrict__ w_decay, const float* __restrict__ startv,
                        u16* __restrict__ rs, u16* __restrict__ hcat){
  int c = blockIdx.x*256 + threadIdx.x;
  int chunk = blockIdx.y, b = blockIdx.z;
  float w = sigm(w_decay[c]);
  float s = startv[((size_t)(b*32+chunk))*1024 + c];
  size_t t0 = (size_t)b*2048 + chunk*64;
  size_t idx = t0*1024 + c;
  size_t idx2 = t0*2048 + 1024 + c;
  for (int i=0;i<64;++i){
    s = w*s + bf2f(kbuf[idx])*bf2f(vbuf[idx]);
    rs[idx] = f2bf(bf2f(rbuf[idx]) * s);
    hcat[idx2] = f2bf(s);
    idx += 1024; idx2 += 2048;
  }
}

// ---------------- routing ----------------
__global__ void route_count(const int* __restrict__ winners, int* __restrict__ offs, int* __restrict__ cursor){
  __shared__ int cnt[8];
  if (threadIdx.x < 8) cnt[threadIdx.x] = 0;
  __syncthreads();
  for (int p = threadIdx.x; p < 8192; p += 256) atomicAdd(&cnt[winners[p]&7], 1);
  __syncthreads();
  if (threadIdx.x == 0){
    int s = 0;
    #pragma unroll
    for (int e=0;e<8;++e){ offs[e]=s; s+=cnt[e]; }
    offs[8]=s;
  }
  if (threadIdx.x < 8) cursor[threadIdx.x] = 0;
}
__global__ void route_scatter(const int* __restrict__ winners, const int* __restrict__ offs,
                              int* __restrict__ cursor, int* __restrict__ idx_all){
  int p = blockIdx.x*256 + threadIdx.x;
  if (p < 8192){
    int e = winners[p]&7;
    int pos = offs[e] + atomicAdd(&cursor[e], 1);
    idx_all[pos] = p>>1;
  }
}

// ---------------- 256x128 bf16 MFMA GEMM: 8 waves, BK=32, ring-3, depth-2 prefetch ----------------
struct GArgs {
  const u16* A; const u16* B;
  long long lda, bstride;
  int K, Mdense, eBase, nxt, kdiv;
  const int* offs; const int* idx_all;
  const float* v_first; const float* g_v;
  u16* rbuf; u16* kbuf; u16* vbuf;
  u16* act; u16* part;
};

#define GLL(gp, lp) __builtin_amdgcn_global_load_lds((const __attribute__((address_space(1))) void*)(gp), \
                                                     (__attribute__((address_space(3))) void*)(lp), 16, 0, 0)

template<int EPI, int GATHER>
__global__ __launch_bounds__(512,4) void gemm_k(GArgs g){
  int e = g.eBase + blockIdx.z;
  int rbase = 0, m = g.Mdense;
  if (g.offs){ rbase = g.offs[e]; m = g.offs[e+1] - rbase; }
  if ((int)blockIdx.y * 256 >= m) return;
  const int xt = (int)blockIdx.x % g.nxt;
  const int ksplit = (int)blockIdx.x / g.nxt;
  const long long kOff = (long long)ksplit * g.kdiv;
  __shared__ char smem[73728];          // 3 bufs x (A[256][32] 16KB + B[128][32] 8KB)
  const int tid = threadIdx.x, lane = tid&63, wave = tid>>6;
  const int wr = wave>>1, wc = wave&1;   // 4 m-waves x 2 n-waves
  const int nk = g.kdiv >> 5;

  const int srowi = tid>>2;             // 0..127 (staging row)
  const long long scol = (long long)((tid&3)*8);

  const u16* bBase0 = g.B + (long long)blockIdx.z*g.bstride
                    + ((long long)(xt*128) + srowi)*(long long)g.K + kOff + scol;

  int aRd[4], bRd[4];
  #pragma unroll
  for (int q=0;q<4;++q){
    aRd[q] = (wr*64 + q*16 + (lane&15))*64 + (lane>>4)*16;
    bRd[q] = 16384 + (wc*64 + q*16 + (lane&15))*64 + (lane>>4)*16;
  }

  for (int mt = blockIdx.y; mt*256 < m; mt += gridDim.y){
    const u16 *aP0, *aP1;
    {
      int g0 = mt*256 + srowi;       g0 = g0 < m ? g0 : m-1;
      int g1 = mt*256 + 128 + srowi; g1 = g1 < m ? g1 : m-1;
      long long r0, r1;
      if (GATHER){ r0 = g.idx_all[rbase+g0]; r1 = g.idx_all[rbase+g1]; }
      else if (g.offs){ r0 = rbase+g0; r1 = rbase+g1; }
      else { r0 = g0; r1 = g1; }
      aP0 = g.A + r0*g.lda + kOff + scol;
      aP1 = g.A + r1*g.lda + kOff + scol;
    }
    const u16* bP0 = bBase0;

    f32x4 acc[4][4];
    #pragma unroll
    for (int mm=0;mm<4;++mm)
      #pragma unroll
      for (int nn=0;nn<4;++nn)
        acc[mm][nn] = f32x4{0.f,0.f,0.f,0.f};

    #define STAGE(BUF) do{ \
      char* db = smem + (BUF)*24576 + wave*1024; \
      GLL(aP0, db); GLL(aP1, db+8192); GLL(bP0, db+16384); \
      aP0+=32; aP1+=32; bP0+=32; }while(0)

    STAGE(0); STAGE(1);
    int bufC = 0, bufS = 2;
    for (int ks=0; ks<nk; ++ks){
      if (ks+2 < nk){
        STAGE(bufS); bufS = bufS==2 ? 0 : bufS+1;
        asm volatile("s_waitcnt vmcnt(6)" ::: "memory");
      } else if (ks+1 < nk){
        asm volatile("s_waitcnt vmcnt(3)" ::: "memory");
      } else {
        asm volatile("s_waitcnt vmcnt(0)" ::: "memory");
      }
      asm volatile("s_barrier" ::: "memory");
      const char* base = smem + bufC*24576;
      bf16x8 af[4], bfv[4];
      #pragma unroll
      for (int q=0;q<4;++q) af[q] = *(const bf16x8*)(base + aRd[q]);
      #pragma unroll
      for (int q=0;q<4;++q) bfv[q] = *(const bf16x8*)(base + bRd[q]);
      #pragma unroll
      for (int mm=0;mm<4;++mm)
        #pragma unroll
        for (int nn=0;nn<4;++nn)
          acc[mm][nn] = __builtin_amdgcn_mfma_f32_16x16x32_bf16(af[mm], bfv[nn], acc[mm][nn], 0,0,0);
      asm volatile("s_waitcnt lgkmcnt(0)" ::: "memory");
      asm volatile("s_barrier" ::: "memory");
      bufC = bufC==2 ? 0 : bufC+1;
    }
    #undef STAGE

    // epilogue
    int colB = xt*128 + wc*64 + (lane&15);
    #pragma unroll
    for (int mm=0;mm<4;++mm){
      #pragma unroll
      for (int j=0;j<4;++j){
        int grow = mt*256 + wr*64 + mm*16 + (lane>>4)*4 + j;
        if (grow >= m) continue;
        size_t gr = (size_t)(rbase + grow);
        #pragma unroll
        for (int nn=0;nn<4;++nn){
          int col = colB + nn*16;
          float val = acc[mm][nn][j];
          if (EPI==0){                                   // rkv split (dense: gr == token row)
            if (col < 1024) g.rbuf[gr*1024+col] = f2bf(sigm(val));
            else if (col < 2048) g.kbuf[gr*1024+col-1024] = f2bf(val);
            else {
              int c2 = col-2048;
              float sg = sigm(g.g_v[c2]);
              float vf = g.v_first[gr*1024+c2];
              g.vbuf[gr*1024+c2] = f2bf(val + (vf-val)*sg);
            }
          } else if (EPI==3){                            // relu^2 -> act
            float r_ = fmaxf(val, 0.f);
            g.act[gr*4096+col] = f2bf(r_*r_);
          } else if (EPI==6){                            // gelu -> act
            float t3 = val*val*val;
            float th = tanhf(0.79788456080286535588f*(val + 0.044715f*t3));
            g.act[gr*4096+col] = f2bf(0.5f*val*(1.f+th));
          } else {                                       // partial write (EPI 1,2,4,5,7)
            g.part[(size_t)ksplit*PSTRIDE + gr*1024 + col] = f2bf(val);
          }
        }
      }
    }
  }
}

// ---------------- reduce kernels ----------------
__global__ void red_ht(const u16* __restrict__ hcat, const u16* __restrict__ part,
                       const float* __restrict__ bb, u16* __restrict__ ht){
  int c = threadIdx.x*4;
  size_t i = (size_t)blockIdx.x*1024 + c;
  U16x4 p0 = *(const U16x4*)(part + i);
  U16x4 p1 = *(const U16x4*)(part + PSTRIDE + i);
  U16x4 hv = *(const U16x4*)(hcat + (size_t)blockIdx.x*2048 + c);
  U16x4 o;
  #pragma unroll
  for (int j=0;j<4;++j) o.v[j] = f2bf(bf2f(hv.v[j]) + bf2f(p0.v[j]) + bf2f(p1.v[j]) + bb[c+j]);
  *(U16x4*)(ht + i) = o;
}
// experts combine: rwkv rows: 0.5*sigm(p2+p3)*(p0+p1); trans rows: 0.5*(p0+p1+p2+p3)
__global__ void red_moe(const int* __restrict__ offs, const int* __restrict__ idx_all,
                        const u16* __restrict__ part, float* __restrict__ out){
  int gr = blockIdx.x;
  if (gr >= offs[8]) return;
  int tok = idx_all[gr];
  bool isr = gr < offs[6];
  int c = threadIdx.x*4;
  size_t i = (size_t)gr*1024 + c;
  U16x4 p0 = *(const U16x4*)(part + i);
  U16x4 p1 = *(const U16x4*)(part + PSTRIDE + i);
  U16x4 p2 = *(const U16x4*)(part + 2*PSTRIDE + i);
  U16x4 p3 = *(const U16x4*)(part + 3*PSTRIDE + i);
  #pragma unroll
  for (int j=0;j<4;++j){
    float v;
    if (isr){
      float rc = sigm(bf2f(p2.v[j]) + bf2f(p3.v[j]));
      v = 0.5f*(bf2f(p0.v[j]) + bf2f(p1.v[j]))*rc;
    } else {
      v = 0.5f*(bf2f(p0.v[j]) + bf2f(p1.v[j]) + bf2f(p2.v[j]) + bf2f(p3.v[j]));
    }
    atomicAdd(&out[(size_t)tok*1024 + c + j], v);
  }
}

// ---------------- host launch ----------------
extern "C" void kernel_launch(void* const* d_in, const int* in_sizes, int n_in,
                              void* d_out, int out_size, void* d_ws, size_t ws_size,
                              hipStream_t stream) {
  const float* x       = (const float*)d_in[0];
  const float* v_first = (const float*)d_in[1];
  const int*   winners = (const int*)d_in[2];
  const float* ln1_g   = (const float*)d_in[4];
  const float* ln1_b   = (const float*)d_in[5];
  const float* ln2_g   = (const float*)d_in[6];
  const float* ln2_b   = (const float*)d_in[7];
  const float* Wr      = (const float*)d_in[8];
  const float* Wk      = (const float*)d_in[9];
  const float* Wv      = (const float*)d_in[10];
  const float* Wo      = (const float*)d_in[11];
  const float* w_decay = (const float*)d_in[12];
  const float* g_v     = (const float*)d_in[13];
  const float* Wb      = (const float*)d_in[14];
  const float* bb      = (const float*)d_in[15];
  const float* Wk_r    = (const float*)d_in[16];
  const float* Wv_r    = (const float*)d_in[17];
  const float* Wr_r    = (const float*)d_in[18];
  const float* W1_t    = (const float*)d_in[19];
  const float* W2_t    = (const float*)d_in[20];
  float* out = (float*)d_out;

  char* p = (char*)d_ws;
  auto alloc = [&](size_t bytes)->char*{ char* r=p; p += (bytes+255)&~(size_t)255; return r; };
  u16* wTrkv = (u16*)alloc(3072ull*1024*2);
  u16* wTo   = (u16*)alloc(1024ull*1024*2);
  u16* wTb   = (u16*)alloc(1024ull*2048*2);
  u16* wTkr  = (u16*)alloc(6ull*4096*1024*2);
  u16* wTvr  = (u16*)alloc(6ull*1024*4096*2);
  u16* wTrr  = (u16*)alloc(6ull*1024*1024*2);
  u16* wT1   = (u16*)alloc(2ull*4096*1024*2);
  u16* wT2   = (u16*)alloc(2ull*1024*4096*2);
  u16* h1    = (u16*)alloc(4096ull*1024*2);
  u16* rbuf  = (u16*)alloc(4096ull*1024*2);
  u16* kbuf  = (u16*)alloc(4096ull*1024*2);
  u16* vbuf  = (u16*)alloc(4096ull*1024*2);
  u16* rsb   = (u16*)alloc(4096ull*1024*2);
  u16* hcat  = (u16*)alloc(4096ull*2048*2);
  u16* htb   = (u16*)alloc(4096ull*1024*2);
  u16* act   = (u16*)alloc(8192ull*4096*2);
  u16* partial = (u16*)alloc(4ull*8192*1024*2);
  float* carry  = (float*)alloc(2ull*32*1024*4);
  float* startv = (float*)alloc(2ull*32*1024*4);
  int* offs   = (int*)alloc(16*4);
  int* cursor = (int*)alloc(8*4);
  int* idx_all= (int*)alloc(8192*4);

  dim3 B256(256), B512(512);

  // ---- merged weight transpose-convert (one dispatch, 128x64 tiles) ----
  {
    CJobs cj; int base = 0, ji = 0;
    auto add = [&](const float* s, u16* d, int K, int N){
      cj.j[ji++] = CJob{s, d, K, N, base}; base += (K>>7)*(N>>6);
    };
    add(Wr, wTrkv, 1024,1024); add(Wk, wTrkv+1024*1024, 1024,1024);
    add(Wv, wTrkv+2048*1024, 1024,1024); add(Wo, wTo, 1024,1024);
    add(Wb, wTb, 2048,1024);
    for (int e2=0;e2<6;++e2) add(Wk_r + (size_t)e2*1024*4096, wTkr + (size_t)e2*4096*1024, 1024,4096);
    for (int e2=0;e2<6;++e2) add(Wv_r + (size_t)e2*4096*1024, wTvr + (size_t)e2*1024*4096, 4096,1024);
    for (int e2=0;e2<6;++e2) add(Wr_r + (size_t)e2*1024*1024, wTrr + (size_t)e2*1024*1024, 1024,1024);
    for (int e2=0;e2<2;++e2) add(W1_t + (size_t)e2*1024*4096, wT1 + (size_t)e2*4096*1024, 1024,4096);
    for (int e2=0;e2<2;++e2) add(W2_t + (size_t)e2*4096*1024, wT2 + (size_t)e2*1024*4096, 4096,1024);
    conv_all<<<dim3(base,1,1),B256,0,stream>>>(cj);
  }

  // routing
  route_count<<<1,B256,0,stream>>>(winners, offs, cursor);
  route_scatter<<<32,B256,0,stream>>>(winners, offs, cursor, idx_all);

  // LN1 -> h1
  ln_k<<<4096,B256,0,stream>>>(x, ln1_g, ln1_b, h1, 1024);

  // r|k|v = h1 @ [Wr|Wk|Wv]
  {
    GArgs ga{}; ga.A=h1; ga.B=wTrkv; ga.lda=1024; ga.K=1024; ga.Mdense=4096; ga.nxt=24; ga.kdiv=1024;
    ga.v_first=v_first; ga.g_v=g_v; ga.rbuf=rbuf; ga.kbuf=kbuf; ga.vbuf=vbuf;
    gemm_k<0,0><<<dim3(24,16,1),B512,0,stream>>>(ga);
  }

  // scan
  scan_p1<<<dim3(4,32,2),B256,0,stream>>>(kbuf, vbuf, w_decay, carry);
  scan_p2<<<dim3(4,2,1), B256,0,stream>>>(w_decay, carry, startv);
  scan_p3<<<dim3(4,32,2),B256,0,stream>>>(kbuf, vbuf, rbuf, w_decay, startv, rsb, hcat);

  // attout partials (split-K 2) + fused reduce+LN2: out = x+attout, hcat[:, :1024] = LN(out)
  {
    GArgs ga{}; ga.A=rsb; ga.B=wTo; ga.lda=1024; ga.K=1024; ga.Mdense=4096; ga.nxt=8; ga.kdiv=512;
    ga.part=partial;
    gemm_k<1,0><<<dim3(16,16,1),B512,0,stream>>>(ga);
  }
  red_x_ln<<<4096,B256,0,stream>>>(x, partial, ln2_g, ln2_b, out, hcat);

  // bridge partials (split-K 2) + reduce: ht = h + bridge + bb
  {
    GArgs ga{}; ga.A=hcat; ga.B=wTb; ga.lda=2048; ga.K=2048; ga.Mdense=4096; ga.nxt=8; ga.kdiv=1024;
    ga.part=partial;
    gemm_k<2,0><<<dim3(16,16,1),B512,0,stream>>>(ga);
  }
  red_ht<<<4096,B256,0,stream>>>(hcat, partial, bb, htb);

  // RWKV experts: act = relu(h@Wk_r)^2
  {
    GArgs ga{}; ga.A=hcat; ga.B=wTkr; ga.lda=2048; ga.bstride=4096ll*1024; ga.K=1024; ga.nxt=32; ga.kdiv=1024;
    ga.offs=offs; ga.eBase=0; ga.idx_all=idx_all; ga.act=act;
    gemm_k<3,1><<<dim3(32,6,6),B512,0,stream>>>(ga);
  }
  // rec partials (split-K 2) into slots {2,3}
  {
    GArgs ga{}; ga.A=hcat; ga.B=wTrr; ga.lda=2048; ga.bstride=1024ll*1024; ga.K=1024; ga.nxt=8; ga.kdiv=512;
    ga.offs=offs; ga.eBase=0; ga.idx_all=idx_all; ga.part=partial + 2*PSTRIDE;
    gemm_k<4,1><<<dim3(16,6,6),B512,0,stream>>>(ga);
  }
  // rwkv expert out partials (split-K 2)
  {
    GArgs ga{}; ga.A=act; ga.B=wTvr; ga.lda=4096; ga.bstride=1024ll*4096; ga.K=4096; ga.nxt=8; ga.kdiv=2048;
    ga.offs=offs; ga.eBase=0; ga.part=partial;
    gemm_k<5,0><<<dim3(16,6,6),B512,0,stream>>>(ga);
  }
  // trans experts: act = gelu(ht@W1)
  {
    GArgs ga{}; ga.A=htb; ga.B=wT1; ga.lda=1024; ga.bstride=4096ll*1024; ga.K=1024; ga.nxt=32; ga.kdiv=1024;
    ga.offs=offs; ga.eBase=6; ga.idx_all=idx_all; ga.act=act;
    gemm_k<6,1><<<dim3(32,4,2),B512,0,stream>>>(ga);
  }
  // trans expert out partials (split-K 4, slots 0..3; rows disjoint from rwkv)
  {
    GArgs ga{}; ga.A=act; ga.B=wT2; ga.lda=4096; ga.bstride=1024ll*4096; ga.K=4096; ga.nxt=8; ga.kdiv=1024;
    ga.offs=offs; ga.eBase=6; ga.part=partial;
    gemm_k<7,0><<<dim3(32,4,2),B512,0,stream>>>(ga);
  }
  // combine experts into out
  red_moe<<<8192,B256,0,stream>>>(offs, idx_all, partial, out);

  (void)in_sizes; (void)n_in; (void)out_size; (void)ws_size;
}

// Round 10
// 747.514 us; speedup vs baseline: 1.0021x; 1.0021x over previous
//
#include <hip/hip_runtime.h>

typedef unsigned short u16;
typedef __bf16 bf16x8 __attribute__((ext_vector_type(8)));
typedef float f32x4 __attribute__((ext_vector_type(4)));

__device__ __forceinline__ float bf2f(u16 u){ union{unsigned i;float f;}x; x.i=((unsigned)u)<<16; return x.f; }
__device__ __forceinline__ u16 f2bf(float f){ union{float f;unsigned i;}x; x.f=f; unsigned r = x.i + 0x7FFFu + ((x.i>>16)&1u); return (u16)(r>>16); }
__device__ __forceinline__ float sigm(float x){ return 1.f/(1.f+expf(-x)); }

struct __align__(8) U16x4 { u16 v[4]; };

#define PSTRIDE 8388608ull   // elems per split in partial buffer [4][8192][1024]

// ---------------- merged f32 [K][N] -> bf16 [N][K] transpose-convert ----------------
struct CJob { const float* src; u16* dst; int K, N, base; };
struct CJobs { CJob j[27]; };

__global__ void conv_all(CJobs cj){
  __shared__ u16 tile[128][65];
  int id = blockIdx.x;
  int sel = 0;
  #pragma unroll
  for (int i=1;i<27;++i) if (cj.j[i].base <= id) sel = i;
  const float* __restrict__ src = cj.j[sel].src;
  u16* __restrict__ dst = cj.j[sel].dst;
  int K = cj.j[sel].K, N = cj.j[sel].N;
  int lt = id - cj.j[sel].base;
  int tn = N >> 6;
  int k0 = (lt / tn) * 128, n0 = (lt % tn) * 64;
  int tid = threadIdx.x;
  #pragma unroll
  for (int it=0; it<8; ++it){
    int e = it*1024 + tid*4;
    int r = e>>6, c = e&63;
    float4 v = *(const float4*)(src + (size_t)(k0+r)*N + n0 + c);
    tile[r][c+0]=f2bf(v.x); tile[r][c+1]=f2bf(v.y); tile[r][c+2]=f2bf(v.z); tile[r][c+3]=f2bf(v.w);
  }
  __syncthreads();
  #pragma unroll
  for (int it=0; it<8; ++it){
    int e = it*1024 + tid*4;
    int n = e>>7, k = e&127;
    U16x4 o;
    #pragma unroll
    for (int j=0;j<4;++j) o.v[j] = tile[k+j][n];
    *(U16x4*)(dst + (size_t)(n0+n)*K + k0 + k) = o;
  }
}

// ---------------- LayerNorm: f32 [4096][1024] -> bf16 rows (stride ostride) ----------------
__global__ void ln_k(const float* __restrict__ x, const float* __restrict__ g, const float* __restrict__ b,
                     u16* __restrict__ out, int ostride){
  int row = blockIdx.x, tid = threadIdx.x;
  float4 v = *(const float4*)(x + (size_t)row*1024 + tid*4);
  float s = v.x+v.y+v.z+v.w;
  float ss = v.x*v.x+v.y*v.y+v.z*v.z+v.w*v.w;
  #pragma unroll
  for (int o=32;o;o>>=1){ s += __shfl_down(s,o); ss += __shfl_down(ss,o); }
  __shared__ float sm[8];
  int lane = tid&63, wv = tid>>6;
  if (!lane){ sm[wv]=s; sm[4+wv]=ss; }
  __syncthreads();
  s = sm[0]+sm[1]+sm[2]+sm[3]; ss = sm[4]+sm[5]+sm[6]+sm[7];
  float mean = s*(1.f/1024.f);
  float var = ss*(1.f/1024.f) - mean*mean;
  float inv = rsqrtf(var + 1e-5f);
  U16x4 o;
  const float* vp = &v.x;
  #pragma unroll
  for (int j=0;j<4;++j){
    int c = tid*4+j;
    o.v[j] = f2bf((vp[j]-mean)*inv*g[c] + b[c]);
  }
  *(U16x4*)(out + (size_t)row*ostride + tid*4) = o;
}

// ---------------- fused: out = x + p0 + p1 ; hcat[:, :1024] = LN(out) ----------------
__global__ void red_x_ln(const float* __restrict__ x, const u16* __restrict__ part,
                         const float* __restrict__ g, const float* __restrict__ b,
                         float* __restrict__ out, u16* __restrict__ hcat){
  int row = blockIdx.x, tid = threadIdx.x;
  size_t i = (size_t)row*1024 + tid*4;
  U16x4 p0 = *(const U16x4*)(part + i);
  U16x4 p1 = *(const U16x4*)(part + PSTRIDE + i);
  float4 xv = *(const float4*)(x + i);
  float4 v;
  v.x = xv.x + bf2f(p0.v[0]) + bf2f(p1.v[0]);
  v.y = xv.y + bf2f(p0.v[1]) + bf2f(p1.v[1]);
  v.z = xv.z + bf2f(p0.v[2]) + bf2f(p1.v[2]);
  v.w = xv.w + bf2f(p0.v[3]) + bf2f(p1.v[3]);
  *(float4*)(out + i) = v;
  float s = v.x+v.y+v.z+v.w;
  float ss = v.x*v.x+v.y*v.y+v.z*v.z+v.w*v.w;
  #pragma unroll
  for (int o=32;o;o>>=1){ s += __shfl_down(s,o); ss += __shfl_down(ss,o); }
  __shared__ float sm[8];
  int lane = tid&63, wv = tid>>6;
  if (!lane){ sm[wv]=s; sm[4+wv]=ss; }
  __syncthreads();
  s = sm[0]+sm[1]+sm[2]+sm[3]; ss = sm[4]+sm[5]+sm[6]+sm[7];
  float mean = s*(1.f/1024.f);
  float var = ss*(1.f/1024.f) - mean*mean;
  float inv = rsqrtf(var + 1e-5f);
  U16x4 o;
  const float* vp = &v.x;
  #pragma unroll
  for (int j=0;j<4;++j){
    int c = tid*4+j;
    o.v[j] = f2bf((vp[j]-mean)*inv*g[c] + b[c]);
  }
  *(U16x4*)(hcat + (size_t)row*2048 + tid*4) = o;
}

// ---------------- 3-phase chunked linear scan ----------------
__global__ void scan_p1(const u16* __restrict__ kbuf, const u16* __restrict__ vbuf,
                        const float* __restrict__ w_decay, float* __restrict__ carry){
  int c = blockIdx.x*256 + threadIdx.x;
  int chunk = blockIdx.y, b = blockIdx.z;
  float w = sigm(w_decay[c]);
  float s = 0.f;
  size_t idx = ((size_t)(b*2048 + chunk*64))*1024 + c;
  #pragma unroll 4
  for (int i=0;i<64;++i){ s = w*s + bf2f(kbuf[idx])*bf2f(vbuf[idx]); idx += 1024; }
  carry[((size_t)(b*32+chunk))*1024 + c] = s;
}
__global__ void scan_p2(const float* __restrict__ w_decay, const float* __restrict__ carry,
                        float* __restrict__ startv){
  int c = blockIdx.x*256 + threadIdx.x;
  int b = blockIdx.y;
  float w = sigm(w_decay[c]);
  float wL = w;
  #pragma unroll
  for (int i=0;i<6;++i) wL *= wL;   // w^64
  float p = 0.f;
  for (int j=0;j<32;++j){
    size_t id = ((size_t)(b*32+j))*1024 + c;
    startv[id] = p;
    p = wL*p + carry[id];
  }
}
__global__ void scan_p3(const u16* __restrict__ kbuf, const u16* __restrict__ vbuf, const u16* __restrict__ rbuf,
                        const float* __restrict__ w_decay, const float* __restrict__ startv,
                        u16* __restrict__ rs, u16* __restrict__ hcat){
  int c = blockIdx.x*256 + threadIdx.x;
  int chunk = blockIdx.y, b = blockIdx.z;
  float w = sigm(w_decay[c]);
  float s = startv[((size_t)(b*32+chunk))*1024 + c];
  size_t t0 = (size_t)b*2048 + chunk*64;
  size_t idx = t0*1024 + c;
  size_t idx2 = t0*2048 + 1024 + c;
  for (int i=0;i<64;++i){
    s = w*s + bf2f(kbuf[idx])*bf2f(vbuf[idx]);
    rs[idx] = f2bf(bf2f(rbuf[idx]) * s);
    hcat[idx2] = f2bf(s);
    idx += 1024; idx2 += 2048;
  }
}

// ---------------- routing ----------------
__global__ void route_count(const int* __restrict__ winners, int* __restrict__ offs, int* __restrict__ cursor){
  __shared__ int cnt[8];
  if (threadIdx.x < 8) cnt[threadIdx.x] = 0;
  __syncthreads();
  for (int p = threadIdx.x; p < 8192; p += 256) atomicAdd(&cnt[winners[p]&7], 1);
  __syncthreads();
  if (threadIdx.x == 0){
    int s = 0;
    #pragma unroll
    for (int e=0;e<8;++e){ offs[e]=s; s+=cnt[e]; }
    offs[8]=s;
  }
  if (threadIdx.x < 8) cursor[threadIdx.x] = 0;
}
__global__ void route_scatter(const int* __restrict__ winners, const int* __restrict__ offs,
                              int* __restrict__ cursor, int* __restrict__ idx_all){
  int p = blockIdx.x*256 + threadIdx.x;
  if (p < 8192){
    int e = winners[p]&7;
    int pos = offs[e] + atomicAdd(&cursor[e], 1);
    idx_all[pos] = p>>1;
  }
}

// ---------------- universal 128x128 bf16 MFMA GEMM: BK=32, ring-3, depth-2 prefetch ----------------
struct GArgs {
  const u16* A; const u16* B;
  long long lda, bstride;
  int K, Mdense, eBase, nxt, kdiv;
  const int* offs; const int* idx_all;
  const float* v_first; const float* g_v;
  u16* rbuf; u16* kbuf; u16* vbuf;
  u16* act; u16* part;
};

#define GLL(gp, lp) __builtin_amdgcn_global_load_lds((const __attribute__((address_space(1))) void*)(gp), \
                                                     (__attribute__((address_space(3))) void*)(lp), 16, 0, 0)

template<int EPI, int GATHER>
__global__ __launch_bounds__(256,3) void gemm_k(GArgs g){
  int e = g.eBase + blockIdx.z;
  int rbase = 0, m = g.Mdense;
  if (g.offs){ rbase = g.offs[e]; m = g.offs[e+1] - rbase; }
  if ((int)blockIdx.y * 128 >= m) return;
  const int xt = (int)blockIdx.x % g.nxt;
  const int ksplit = (int)blockIdx.x / g.nxt;
  const long long kOff = (long long)ksplit * g.kdiv;
  __shared__ char smem[49152];          // 3 bufs x (A[128][32] 8KB + B[128][32] 8KB)
  const int tid = threadIdx.x, lane = tid&63, wave = tid>>6;
  const int wr = wave>>1, wc = wave&1;
  const int nk = g.kdiv >> 5;

  const int srowi = tid>>2;             // 0..63
  const long long scol = (long long)((tid&3)*8);

  const u16* bBase0 = g.B + (long long)blockIdx.z*g.bstride
                    + ((long long)(xt*128) + srowi)*(long long)g.K + kOff + scol;
  const u16* bBase1 = bBase0 + 64ll*(long long)g.K;

  int aRd[4], bRd[4];
  #pragma unroll
  for (int q=0;q<4;++q){
    aRd[q] = (wr*64 + q*16 + (lane&15))*64 + (lane>>4)*16;
    bRd[q] = 8192 + (wc*64 + q*16 + (lane&15))*64 + (lane>>4)*16;
  }

  for (int mt = blockIdx.y; mt*128 < m; mt += gridDim.y){
    const u16 *aP0, *aP1;
    {
      int g0 = mt*128 + srowi;       g0 = g0 < m ? g0 : m-1;
      int g1 = mt*128 + 64 + srowi;  g1 = g1 < m ? g1 : m-1;
      long long r0, r1;
      if (GATHER){ r0 = g.idx_all[rbase+g0]; r1 = g.idx_all[rbase+g1]; }
      else if (g.offs){ r0 = rbase+g0; r1 = rbase+g1; }
      else { r0 = g0; r1 = g1; }
      aP0 = g.A + r0*g.lda + kOff + scol;
      aP1 = g.A + r1*g.lda + kOff + scol;
    }
    const u16* bP0 = bBase0;
    const u16* bP1 = bBase1;

    f32x4 acc[4][4];
    #pragma unroll
    for (int mm=0;mm<4;++mm)
      #pragma unroll
      for (int nn=0;nn<4;++nn)
        acc[mm][nn] = f32x4{0.f,0.f,0.f,0.f};

    #define STAGE(BUF) do{ \
      char* db = smem + (BUF)*16384 + wave*1024; \
      GLL(aP0, db); GLL(aP1, db+4096); GLL(bP0, db+8192); GLL(bP1, db+12288); \
      aP0+=32; aP1+=32; bP0+=32; bP1+=32; }while(0)

    STAGE(0); STAGE(1);
    int bufC = 0, bufS = 2;
    for (int ks=0; ks<nk; ++ks){
      if (ks+2 < nk){
        STAGE(bufS); bufS = bufS==2 ? 0 : bufS+1;
        asm volatile("s_waitcnt vmcnt(8)" ::: "memory");
      } else if (ks+1 < nk){
        asm volatile("s_waitcnt vmcnt(4)" ::: "memory");
      } else {
        asm volatile("s_waitcnt vmcnt(0)" ::: "memory");
      }
      asm volatile("s_barrier" ::: "memory");
      const char* base = smem + bufC*16384;
      bf16x8 af[4], bfv[4];
      #pragma unroll
      for (int q=0;q<4;++q) af[q] = *(const bf16x8*)(base + aRd[q]);
      #pragma unroll
      for (int q=0;q<4;++q) bfv[q] = *(const bf16x8*)(base + bRd[q]);
      #pragma unroll
      for (int mm=0;mm<4;++mm)
        #pragma unroll
        for (int nn=0;nn<4;++nn)
          acc[mm][nn] = __builtin_amdgcn_mfma_f32_16x16x32_bf16(af[mm], bfv[nn], acc[mm][nn], 0,0,0);
      asm volatile("s_waitcnt lgkmcnt(0)" ::: "memory");
      asm volatile("s_barrier" ::: "memory");
      bufC = bufC==2 ? 0 : bufC+1;
    }
    #undef STAGE

    // epilogue
    int colB = xt*128 + wc*64 + (lane&15);
    #pragma unroll
    for (int mm=0;mm<4;++mm){
      #pragma unroll
      for (int j=0;j<4;++j){
        int grow = mt*128 + wr*64 + mm*16 + (lane>>4)*4 + j;
        if (grow >= m) continue;
        size_t gr = (size_t)(rbase + grow);
        #pragma unroll
        for (int nn=0;nn<4;++nn){
          int col = colB + nn*16;
          float val = acc[mm][nn][j];
          if (EPI==0){                                   // rkv split (dense: gr == token row)
            if (col < 1024) g.rbuf[gr*1024+col] = f2bf(sigm(val));
            else if (col < 2048) g.kbuf[gr*1024+col-1024] = f2bf(val);
            else {
              int c2 = col-2048;
              float sg = sigm(g.g_v[c2]);
              float vf = g.v_first[gr*1024+c2];
              g.vbuf[gr*1024+c2] = f2bf(val + (vf-val)*sg);
            }
          } else {                                       // partial write (EPI 1,2)
            g.part[(size_t)ksplit*PSTRIDE + gr*1024 + col] = f2bf(val);
          }
        }
      }
    }
  }
}

// ---------------- merged expert GEMMs (two phases, z-demux) ----------------
struct MoeArgs {
  const u16* hcat; const u16* htb; const u16* act;
  const u16* wTkr; const u16* wT1; const u16* wTrr; const u16* wTvr; const u16* wT2;
  const int* offs; const int* idx_all;
  u16* actw; u16* part;
};

template<int PHASE>
__global__ __launch_bounds__(256,3) void gemm_moe(MoeArgs g){
  int z = blockIdx.z;
  const u16 *Ap, *Bp; long long lda; int K, kdiv, nxt, e, epi;
  if (PHASE==0){
    if (z < 6){ e=z;   Ap=g.hcat; lda=2048; Bp=g.wTkr + (long long)z*4096*1024;     K=1024; kdiv=1024; nxt=32; epi=0; }
    else if (z < 8){ e=z; Ap=g.htb; lda=1024; Bp=g.wT1 + (long long)(z-6)*4096*1024; K=1024; kdiv=1024; nxt=32; epi=1; }
    else { e=z-8; Ap=g.hcat; lda=2048; Bp=g.wTrr + (long long)(z-8)*1024*1024;      K=1024; kdiv=512;  nxt=8;  epi=2; }
  } else {
    if (z < 6){ e=z; Ap=g.act; lda=4096; Bp=g.wTvr + (long long)z*1024*4096;        K=4096; kdiv=2048; nxt=8;  epi=3; }
    else { e=z;     Ap=g.act; lda=4096; Bp=g.wT2 + (long long)(z-6)*1024*4096;      K=4096; kdiv=1024; nxt=8;  epi=4; }
  }
  if ((int)blockIdx.x >= nxt * (K / kdiv)) return;
  int rbase = g.offs[e], m = g.offs[e+1] - rbase;
  if ((int)blockIdx.y * 128 >= m) return;
  const int xt = (int)blockIdx.x % nxt;
  const int ksplit = (int)blockIdx.x / nxt;
  const long long kOff = (long long)ksplit * kdiv;
  __shared__ char smem[49152];
  const int tid = threadIdx.x, lane = tid&63, wave = tid>>6;
  const int wr = wave>>1, wc = wave&1;
  const int nk = kdiv >> 5;

  const int srowi = tid>>2;
  const long long scol = (long long)((tid&3)*8);

  const u16* bBase0 = Bp + ((long long)(xt*128) + srowi)*(long long)K + kOff + scol;
  const u16* bBase1 = bBase0 + 64ll*(long long)K;

  int aRd[4], bRd[4];
  #pragma unroll
  for (int q=0;q<4;++q){
    aRd[q] = (wr*64 + q*16 + (lane&15))*64 + (lane>>4)*16;
    bRd[q] = 8192 + (wc*64 + q*16 + (lane&15))*64 + (lane>>4)*16;
  }

  for (int mt = blockIdx.y; mt*128 < m; mt += gridDim.y){
    const u16 *aP0, *aP1;
    {
      int g0 = mt*128 + srowi;       g0 = g0 < m ? g0 : m-1;
      int g1 = mt*128 + 64 + srowi;  g1 = g1 < m ? g1 : m-1;
      long long r0, r1;
      if (epi <= 2){ r0 = g.idx_all[rbase+g0]; r1 = g.idx_all[rbase+g1]; }
      else { r0 = rbase+g0; r1 = rbase+g1; }
      aP0 = Ap + r0*lda + kOff + scol;
      aP1 = Ap + r1*lda + kOff + scol;
    }
    const u16* bP0 = bBase0;
    const u16* bP1 = bBase1;

    f32x4 acc[4][4];
    #pragma unroll
    for (int mm=0;mm<4;++mm)
      #pragma unroll
      for (int nn=0;nn<4;++nn)
        acc[mm][nn] = f32x4{0.f,0.f,0.f,0.f};

    #define STAGE(BUF) do{ \
      char* db = smem + (BUF)*16384 + wave*1024; \
      GLL(aP0, db); GLL(aP1, db+4096); GLL(bP0, db+8192); GLL(bP1, db+12288); \
      aP0+=32; aP1+=32; bP0+=32; bP1+=32; }while(0)

    STAGE(0); STAGE(1);
    int bufC = 0, bufS = 2;
    for (int ks=0; ks<nk; ++ks){
      if (ks+2 < nk){
        STAGE(bufS); bufS = bufS==2 ? 0 : bufS+1;
        asm volatile("s_waitcnt vmcnt(8)" ::: "memory");
      } else if (ks+1 < nk){
        asm volatile("s_waitcnt vmcnt(4)" ::: "memory");
      } else {
        asm volatile("s_waitcnt vmcnt(0)" ::: "memory");
      }
      asm volatile("s_barrier" ::: "memory");
      const char* base = smem + bufC*16384;
      bf16x8 af[4], bfv[4];
      #pragma unroll
      for (int q=0;q<4;++q) af[q] = *(const bf16x8*)(base + aRd[q]);
      #pragma unroll
      for (int q=0;q<4;++q) bfv[q] = *(const bf16x8*)(base + bRd[q]);
      #pragma unroll
      for (int mm=0;mm<4;++mm)
        #pragma unroll
        for (int nn=0;nn<4;++nn)
          acc[mm][nn] = __builtin_amdgcn_mfma_f32_16x16x32_bf16(af[mm], bfv[nn], acc[mm][nn], 0,0,0);
      asm volatile("s_waitcnt lgkmcnt(0)" ::: "memory");
      asm volatile("s_barrier" ::: "memory");
      bufC = bufC==2 ? 0 : bufC+1;
    }
    #undef STAGE

    int colB = xt*128 + wc*64 + (lane&15);
    #pragma unroll
    for (int mm=0;mm<4;++mm){
      #pragma unroll
      for (int j=0;j<4;++j){
        int grow = mt*128 + wr*64 + mm*16 + (lane>>4)*4 + j;
        if (grow >= m) continue;
        size_t gr = (size_t)(rbase + grow);
        #pragma unroll
        for (int nn=0;nn<4;++nn){
          int col = colB + nn*16;
          float val = acc[mm][nn][j];
          if (epi == 0){                        // relu^2 -> act
            float r_ = fmaxf(val, 0.f);
            g.actw[gr*4096+col] = f2bf(r_*r_);
          } else if (epi == 1){                 // gelu -> act
            float t3 = val*val*val;
            float th = tanhf(0.79788456080286535588f*(val + 0.044715f*t3));
            g.actw[gr*4096+col] = f2bf(0.5f*val*(1.f+th));
          } else if (epi == 2){                 // rec partials, slots 2,3
            g.part[(size_t)(2+ksplit)*PSTRIDE + gr*1024 + col] = f2bf(val);
          } else {                              // expert-out partials, slots 0..3
            g.part[(size_t)ksplit*PSTRIDE + gr*1024 + col] = f2bf(val);
          }
        }
      }
    }
  }
}

// ---------------- reduce kernels ----------------
__global__ void red_ht(const u16* __restrict__ hcat, const u16* __restrict__ part,
                       const float* __restrict__ bb, u16* __restrict__ ht){
  int c = threadIdx.x*4;
  size_t i = (size_t)blockIdx.x*1024 + c;
  U16x4 p0 = *(const U16x4*)(part + i);
  U16x4 p1 = *(const U16x4*)(part + PSTRIDE + i);
  U16x4 hv = *(const U16x4*)(hcat + (size_t)blockIdx.x*2048 + c);
  U16x4 o;
  #pragma unroll
  for (int j=0;j<4;++j) o.v[j] = f2bf(bf2f(hv.v[j]) + bf2f(p0.v[j]) + bf2f(p1.v[j]) + bb[c+j]);
  *(U16x4*)(ht + i) = o;
}
// experts combine: rwkv rows: 0.5*sigm(p2+p3)*(p0+p1); trans rows: 0.5*(p0+p1+p2+p3)
__global__ void red_moe(const int* __restrict__ offs, const int* __restrict__ idx_all,
                        const u16* __restrict__ part, float* __restrict__ out){
  int gr = blockIdx.x;
  if (gr >= offs[8]) return;
  int tok = idx_all[gr];
  bool isr = gr < offs[6];
  int c = threadIdx.x*4;
  size_t i = (size_t)gr*1024 + c;
  U16x4 p0 = *(const U16x4*)(part + i);
  U16x4 p1 = *(const U16x4*)(part + PSTRIDE + i);
  U16x4 p2 = *(const U16x4*)(part + 2*PSTRIDE + i);
  U16x4 p3 = *(const U16x4*)(part + 3*PSTRIDE + i);
  #pragma unroll
  for (int j=0;j<4;++j){
    float v;
    if (isr){
      float rc = sigm(bf2f(p2.v[j]) + bf2f(p3.v[j]));
      v = 0.5f*(bf2f(p0.v[j]) + bf2f(p1.v[j]))*rc;
    } else {
      v = 0.5f*(bf2f(p0.v[j]) + bf2f(p1.v[j]) + bf2f(p2.v[j]) + bf2f(p3.v[j]));
    }
    atomicAdd(&out[(size_t)tok*1024 + c + j], v);
  }
}

// ---------------- host launch ----------------
extern "C" void kernel_launch(void* const* d_in, const int* in_sizes, int n_in,
                              void* d_out, int out_size, void* d_ws, size_t ws_size,
                              hipStream_t stream) {
  const float* x       = (const float*)d_in[0];
  const float* v_first = (const float*)d_in[1];
  const int*   winners = (const int*)d_in[2];
  const float* ln1_g   = (const float*)d_in[4];
  const float* ln1_b   = (const float*)d_in[5];
  const float* ln2_g   = (const float*)d_in[6];
  const float* ln2_b   = (const float*)d_in[7];
  const float* Wr      = (const float*)d_in[8];
  const float* Wk      = (const float*)d_in[9];
  const float* Wv      = (const float*)d_in[10];
  const float* Wo      = (const float*)d_in[11];
  const float* w_decay = (const float*)d_in[12];
  const float* g_v     = (const float*)d_in[13];
  const float* Wb      = (const float*)d_in[14];
  const float* bb      = (const float*)d_in[15];
  const float* Wk_r    = (const float*)d_in[16];
  const float* Wv_r    = (const float*)d_in[17];
  const float* Wr_r    = (const float*)d_in[18];
  const float* W1_t    = (const float*)d_in[19];
  const float* W2_t    = (const float*)d_in[20];
  float* out = (float*)d_out;

  char* p = (char*)d_ws;
  auto alloc = [&](size_t bytes)->char*{ char* r=p; p += (bytes+255)&~(size_t)255; return r; };
  u16* wTrkv = (u16*)alloc(3072ull*1024*2);
  u16* wTo   = (u16*)alloc(1024ull*1024*2);
  u16* wTb   = (u16*)alloc(1024ull*2048*2);
  u16* wTkr  = (u16*)alloc(6ull*4096*1024*2);
  u16* wTvr  = (u16*)alloc(6ull*1024*4096*2);
  u16* wTrr  = (u16*)alloc(6ull*1024*1024*2);
  u16* wT1   = (u16*)alloc(2ull*4096*1024*2);
  u16* wT2   = (u16*)alloc(2ull*1024*4096*2);
  u16* h1    = (u16*)alloc(4096ull*1024*2);
  u16* rbuf  = (u16*)alloc(4096ull*1024*2);
  u16* kbuf  = (u16*)alloc(4096ull*1024*2);
  u16* vbuf  = (u16*)alloc(4096ull*1024*2);
  u16* rsb   = (u16*)alloc(4096ull*1024*2);
  u16* hcat  = (u16*)alloc(4096ull*2048*2);
  u16* htb   = (u16*)alloc(4096ull*1024*2);
  u16* act   = (u16*)alloc(8192ull*4096*2);
  u16* partial = (u16*)alloc(4ull*8192*1024*2);
  float* carry  = (float*)alloc(2ull*32*1024*4);
  float* startv = (float*)alloc(2ull*32*1024*4);
  int* offs   = (int*)alloc(16*4);
  int* cursor = (int*)alloc(8*4);
  int* idx_all= (int*)alloc(8192*4);

  dim3 B256(256);

  // ---- merged weight transpose-convert (one dispatch, 128x64 tiles) ----
  {
    CJobs cj; int base = 0, ji = 0;
    auto add = [&](const float* s, u16* d, int K, int N){
      cj.j[ji++] = CJob{s, d, K, N, base}; base += (K>>7)*(N>>6);
    };
    add(Wr, wTrkv, 1024,1024); add(Wk, wTrkv+1024*1024, 1024,1024);
    add(Wv, wTrkv+2048*1024, 1024,1024); add(Wo, wTo, 1024,1024);
    add(Wb, wTb, 2048,1024);
    for (int e2=0;e2<6;++e2) add(Wk_r + (size_t)e2*1024*4096, wTkr + (size_t)e2*4096*1024, 1024,4096);
    for (int e2=0;e2<6;++e2) add(Wv_r + (size_t)e2*4096*1024, wTvr + (size_t)e2*1024*4096, 4096,1024);
    for (int e2=0;e2<6;++e2) add(Wr_r + (size_t)e2*1024*1024, wTrr + (size_t)e2*1024*1024, 1024,1024);
    for (int e2=0;e2<2;++e2) add(W1_t + (size_t)e2*1024*4096, wT1 + (size_t)e2*4096*1024, 1024,4096);
    for (int e2=0;e2<2;++e2) add(W2_t + (size_t)e2*4096*1024, wT2 + (size_t)e2*1024*4096, 4096,1024);
    conv_all<<<dim3(base,1,1),B256,0,stream>>>(cj);
  }

  // routing
  route_count<<<1,B256,0,stream>>>(winners, offs, cursor);
  route_scatter<<<32,B256,0,stream>>>(winners, offs, cursor, idx_all);

  // LN1 -> h1
  ln_k<<<4096,B256,0,stream>>>(x, ln1_g, ln1_b, h1, 1024);

  // r|k|v = h1 @ [Wr|Wk|Wv]
  {
    GArgs ga{}; ga.A=h1; ga.B=wTrkv; ga.lda=1024; ga.K=1024; ga.Mdense=4096; ga.nxt=24; ga.kdiv=1024;
    ga.v_first=v_first; ga.g_v=g_v; ga.rbuf=rbuf; ga.kbuf=kbuf; ga.vbuf=vbuf;
    gemm_k<0,0><<<dim3(24,32,1),B256,0,stream>>>(ga);
  }

  // scan
  scan_p1<<<dim3(4,32,2),B256,0,stream>>>(kbuf, vbuf, w_decay, carry);
  scan_p2<<<dim3(4,2,1), B256,0,stream>>>(w_decay, carry, startv);
  scan_p3<<<dim3(4,32,2),B256,0,stream>>>(kbuf, vbuf, rbuf, w_decay, startv, rsb, hcat);

  // attout partials (split-K 2) + fused reduce+LN2: out = x+attout, hcat[:, :1024] = LN(out)
  {
    GArgs ga{}; ga.A=rsb; ga.B=wTo; ga.lda=1024; ga.K=1024; ga.Mdense=4096; ga.nxt=8; ga.kdiv=512;
    ga.part=partial;
    gemm_k<1,0><<<dim3(16,32,1),B256,0,stream>>>(ga);
  }
  red_x_ln<<<4096,B256,0,stream>>>(x, partial, ln2_g, ln2_b, out, hcat);

  // bridge partials (split-K 2) + reduce: ht = h + bridge + bb
  {
    GArgs ga{}; ga.A=hcat; ga.B=wTb; ga.lda=2048; ga.K=2048; ga.Mdense=4096; ga.nxt=8; ga.kdiv=1024;
    ga.part=partial;
    gemm_k<2,0><<<dim3(16,32,1),B256,0,stream>>>(ga);
  }
  red_ht<<<4096,B256,0,stream>>>(hcat, partial, bb, htb);

  // merged expert phase A: relu^2(hcat@Wk_r) x6 | gelu(htb@W1) x2 | rec partials x6
  {
    MoeArgs ma{};
    ma.hcat=hcat; ma.htb=htb; ma.act=act;
    ma.wTkr=wTkr; ma.wT1=wT1; ma.wTrr=wTrr; ma.wTvr=wTvr; ma.wT2=wT2;
    ma.offs=offs; ma.idx_all=idx_all; ma.actw=act; ma.part=partial;
    gemm_moe<0><<<dim3(32,6,14),B256,0,stream>>>(ma);
    // merged expert phase B: (act@Wv_r) x6 split2 | (act@W2) x2 split4
    gemm_moe<1><<<dim3(32,6,8),B256,0,stream>>>(ma);
  }
  // combine experts into out
  red_moe<<<8192,B256,0,stream>>>(offs, idx_all, partial, out);

  (void)in_sizes; (void)n_in; (void)out_size; (void)ws_size;
}

// Round 11
// 712.646 us; speedup vs baseline: 1.0511x; 1.0489x over previous
//
#include <hip/hip_runtime.h>

typedef unsigned short u16;
typedef __bf16 bf16x8 __attribute__((ext_vector_type(8)));
typedef float f32x4 __attribute__((ext_vector_type(4)));

__device__ __forceinline__ float bf2f(u16 u){ union{unsigned i;float f;}x; x.i=((unsigned)u)<<16; return x.f; }
__device__ __forceinline__ u16 f2bf(float f){ union{float f;unsigned i;}x; x.f=f; unsigned r = x.i + 0x7FFFu + ((x.i>>16)&1u); return (u16)(r>>16); }
__device__ __forceinline__ float sigm(float x){ return 1.f/(1.f+expf(-x)); }

struct __align__(8) U16x4 { u16 v[4]; };

#define PSTRIDE 8388608ull   // elems per split in partial buffer [4][8192][1024]

// ---------------- merged f32 [K][N] -> bf16 [N][K] transpose-convert ----------------
struct CJob { const float* src; u16* dst; int K, N, base; };
struct CJobs { CJob j[27]; };

__global__ void conv_all(CJobs cj){
  __shared__ u16 tile[128][65];
  int id = blockIdx.x;
  int sel = 0;
  #pragma unroll
  for (int i=1;i<27;++i) if (cj.j[i].base <= id) sel = i;
  const float* __restrict__ src = cj.j[sel].src;
  u16* __restrict__ dst = cj.j[sel].dst;
  int K = cj.j[sel].K, N = cj.j[sel].N;
  int lt = id - cj.j[sel].base;
  int tn = N >> 6;
  int k0 = (lt / tn) * 128, n0 = (lt % tn) * 64;
  int tid = threadIdx.x;
  #pragma unroll
  for (int it=0; it<8; ++it){
    int e = it*1024 + tid*4;
    int r = e>>6, c = e&63;
    float4 v = *(const float4*)(src + (size_t)(k0+r)*N + n0 + c);
    tile[r][c+0]=f2bf(v.x); tile[r][c+1]=f2bf(v.y); tile[r][c+2]=f2bf(v.z); tile[r][c+3]=f2bf(v.w);
  }
  __syncthreads();
  #pragma unroll
  for (int it=0; it<8; ++it){
    int e = it*1024 + tid*4;
    int n = e>>7, k = e&127;
    U16x4 o;
    #pragma unroll
    for (int j=0;j<4;++j) o.v[j] = tile[k+j][n];
    *(U16x4*)(dst + (size_t)(n0+n)*K + k0 + k) = o;
  }
}

// ---------------- LayerNorm: f32 [4096][1024] -> bf16 rows (stride ostride) ----------------
__global__ void ln_k(const float* __restrict__ x, const float* __restrict__ g, const float* __restrict__ b,
                     u16* __restrict__ out, int ostride){
  int row = blockIdx.x, tid = threadIdx.x;
  float4 v = *(const float4*)(x + (size_t)row*1024 + tid*4);
  float s = v.x+v.y+v.z+v.w;
  float ss = v.x*v.x+v.y*v.y+v.z*v.z+v.w*v.w;
  #pragma unroll
  for (int o=32;o;o>>=1){ s += __shfl_down(s,o); ss += __shfl_down(ss,o); }
  __shared__ float sm[8];
  int lane = tid&63, wv = tid>>6;
  if (!lane){ sm[wv]=s; sm[4+wv]=ss; }
  __syncthreads();
  s = sm[0]+sm[1]+sm[2]+sm[3]; ss = sm[4]+sm[5]+sm[6]+sm[7];
  float mean = s*(1.f/1024.f);
  float var = ss*(1.f/1024.f) - mean*mean;
  float inv = rsqrtf(var + 1e-5f);
  U16x4 o;
  const float* vp = &v.x;
  #pragma unroll
  for (int j=0;j<4;++j){
    int c = tid*4+j;
    o.v[j] = f2bf((vp[j]-mean)*inv*g[c] + b[c]);
  }
  *(U16x4*)(out + (size_t)row*ostride + tid*4) = o;
}

// ---------------- fused: out = x + p0 + p1 ; hcat[:, :1024] = LN(out) ----------------
__global__ void red_x_ln(const float* __restrict__ x, const u16* __restrict__ part,
                         const float* __restrict__ g, const float* __restrict__ b,
                         float* __restrict__ out, u16* __restrict__ hcat){
  int row = blockIdx.x, tid = threadIdx.x;
  size_t i = (size_t)row*1024 + tid*4;
  U16x4 p0 = *(const U16x4*)(part + i);
  U16x4 p1 = *(const U16x4*)(part + PSTRIDE + i);
  float4 xv = *(const float4*)(x + i);
  float4 v;
  v.x = xv.x + bf2f(p0.v[0]) + bf2f(p1.v[0]);
  v.y = xv.y + bf2f(p0.v[1]) + bf2f(p1.v[1]);
  v.z = xv.z + bf2f(p0.v[2]) + bf2f(p1.v[2]);
  v.w = xv.w + bf2f(p0.v[3]) + bf2f(p1.v[3]);
  *(float4*)(out + i) = v;
  float s = v.x+v.y+v.z+v.w;
  float ss = v.x*v.x+v.y*v.y+v.z*v.z+v.w*v.w;
  #pragma unroll
  for (int o=32;o;o>>=1){ s += __shfl_down(s,o); ss += __shfl_down(ss,o); }
  __shared__ float sm[8];
  int lane = tid&63, wv = tid>>6;
  if (!lane){ sm[wv]=s; sm[4+wv]=ss; }
  __syncthreads();
  s = sm[0]+sm[1]+sm[2]+sm[3]; ss = sm[4]+sm[5]+sm[6]+sm[7];
  float mean = s*(1.f/1024.f);
  float var = ss*(1.f/1024.f) - mean*mean;
  float inv = rsqrtf(var + 1e-5f);
  U16x4 o;
  const float* vp = &v.x;
  #pragma unroll
  for (int j=0;j<4;++j){
    int c = tid*4+j;
    o.v[j] = f2bf((vp[j]-mean)*inv*g[c] + b[c]);
  }
  *(U16x4*)(hcat + (size_t)row*2048 + tid*4) = o;
}

// ---------------- 3-phase chunked linear scan ----------------
__global__ void scan_p1(const u16* __restrict__ kbuf, const u16* __restrict__ vbuf,
                        const float* __restrict__ w_decay, float* __restrict__ carry){
  int c = blockIdx.x*256 + threadIdx.x;
  int chunk = blockIdx.y, b = blockIdx.z;
  float w = sigm(w_decay[c]);
  float s = 0.f;
  size_t idx = ((size_t)(b*2048 + chunk*64))*1024 + c;
  #pragma unroll 4
  for (int i=0;i<64;++i){ s = w*s + bf2f(kbuf[idx])*bf2f(vbuf[idx]); idx += 1024; }
  carry[((size_t)(b*32+chunk))*1024 + c] = s;
}
__global__ void scan_p2(const float* __restrict__ w_decay, const float* __restrict__ carry,
                        float* __restrict__ startv){
  int c = blockIdx.x*256 + threadIdx.x;
  int b = blockIdx.y;
  float w = sigm(w_decay[c]);
  float wL = w;
  #pragma unroll
  for (int i=0;i<6;++i) wL *= wL;   // w^64
  float p = 0.f;
  for (int j=0;j<32;++j){
    size_t id = ((size_t)(b*32+j))*1024 + c;
    startv[id] = p;
    p = wL*p + carry[id];
  }
}
__global__ void scan_p3(const u16* __restrict__ kbuf, const u16* __restrict__ vbuf, const u16* __restrict__ rbuf,
                        const float* __restrict__ w_decay, const float* __restrict__ startv,
                        u16* __restrict__ rs, u16* __restrict__ hcat){
  int c = blockIdx.x*256 + threadIdx.x;
  int chunk = blockIdx.y, b = blockIdx.z;
  float w = sigm(w_decay[c]);
  float s = startv[((size_t)(b*32+chunk))*1024 + c];
  size_t t0 = (size_t)b*2048 + chunk*64;
  size_t idx = t0*1024 + c;
  size_t idx2 = t0*2048 + 1024 + c;
  for (int i=0;i<64;++i){
    s = w*s + bf2f(kbuf[idx])*bf2f(vbuf[idx]);
    rs[idx] = f2bf(bf2f(rbuf[idx]) * s);
    hcat[idx2] = f2bf(s);
    idx += 1024; idx2 += 2048;
  }
}

// ---------------- routing ----------------
__global__ void route_count(const int* __restrict__ winners, int* __restrict__ offs, int* __restrict__ cursor){
  __shared__ int cnt[8];
  if (threadIdx.x < 8) cnt[threadIdx.x] = 0;
  __syncthreads();
  for (int p = threadIdx.x; p < 8192; p += 256) atomicAdd(&cnt[winners[p]&7], 1);
  __syncthreads();
  if (threadIdx.x == 0){
    int s = 0;
    #pragma unroll
    for (int e=0;e<8;++e){ offs[e]=s; s+=cnt[e]; }
    offs[8]=s;
  }
  if (threadIdx.x < 8) cursor[threadIdx.x] = 0;
}
__global__ void route_scatter(const int* __restrict__ winners, const int* __restrict__ offs,
                              int* __restrict__ cursor, int* __restrict__ idx_all){
  int p = blockIdx.x*256 + threadIdx.x;
  if (p < 8192){
    int e = winners[p]&7;
    int pos = offs[e] + atomicAdd(&cursor[e], 1);
    idx_all[pos] = p>>1;
  }
}

// LDS slot swizzle (both-sides XOR, GLL dest stays linear):
//   writer lane l sources global slot ((l&3)^((l>>3)&3)); reader uses slot ((lane>>4)^((lane>>1)&3)).
//   spreads 16 row-lanes over 8 bank-groups -> uniform 2-way (free, m136).

// ---------------- universal 128x128 bf16 MFMA GEMM: BK=32, ring-3, depth-2 prefetch ----------------
struct GArgs {
  const u16* A; const u16* B;
  long long lda, bstride;
  int K, Mdense, eBase, nxt, kdiv;
  const int* offs; const int* idx_all;
  const float* v_first; const float* g_v;
  u16* rbuf; u16* kbuf; u16* vbuf;
  u16* act; u16* part;
};

#define GLL(gp, lp) __builtin_amdgcn_global_load_lds((const __attribute__((address_space(1))) void*)(gp), \
                                                     (__attribute__((address_space(3))) void*)(lp), 16, 0, 0)

template<int EPI, int GATHER>
__global__ __launch_bounds__(256,3) void gemm_k(GArgs g){
  int e = g.eBase + blockIdx.z;
  int rbase = 0, m = g.Mdense;
  if (g.offs){ rbase = g.offs[e]; m = g.offs[e+1] - rbase; }
  if ((int)blockIdx.y * 128 >= m) return;
  const int xt = (int)blockIdx.x % g.nxt;
  const int ksplit = (int)blockIdx.x / g.nxt;
  const long long kOff = (long long)ksplit * g.kdiv;
  __shared__ char smem[49152];          // 3 bufs x (A[128][32] 8KB + B[128][32] 8KB)
  const int tid = threadIdx.x, lane = tid&63, wave = tid>>6;
  const int wr = wave>>1, wc = wave&1;
  const int nk = g.kdiv >> 5;

  const int srowi = tid>>2;             // 0..63
  const long long scol = (long long)((((tid&3) ^ ((tid>>3)&3)))*8);   // pre-swizzled source slot

  const u16* bBase0 = g.B + (long long)blockIdx.z*g.bstride
                    + ((long long)(xt*128) + srowi)*(long long)g.K + kOff + scol;
  const u16* bBase1 = bBase0 + 64ll*(long long)g.K;

  const int sw = ((lane>>4) ^ ((lane>>1)&3)) << 4;                    // swizzled read slot (bytes)
  int aRd[4], bRd[4];
  #pragma unroll
  for (int q=0;q<4;++q){
    aRd[q] = (wr*64 + q*16 + (lane&15))*64 + sw;
    bRd[q] = 8192 + (wc*64 + q*16 + (lane&15))*64 + sw;
  }

  for (int mt = blockIdx.y; mt*128 < m; mt += gridDim.y){
    const u16 *aP0, *aP1;
    {
      int g0 = mt*128 + srowi;       g0 = g0 < m ? g0 : m-1;
      int g1 = mt*128 + 64 + srowi;  g1 = g1 < m ? g1 : m-1;
      long long r0, r1;
      if (GATHER){ r0 = g.idx_all[rbase+g0]; r1 = g.idx_all[rbase+g1]; }
      else if (g.offs){ r0 = rbase+g0; r1 = rbase+g1; }
      else { r0 = g0; r1 = g1; }
      aP0 = g.A + r0*g.lda + kOff + scol;
      aP1 = g.A + r1*g.lda + kOff + scol;
    }
    const u16* bP0 = bBase0;
    const u16* bP1 = bBase1;

    f32x4 acc[4][4];
    #pragma unroll
    for (int mm=0;mm<4;++mm)
      #pragma unroll
      for (int nn=0;nn<4;++nn)
        acc[mm][nn] = f32x4{0.f,0.f,0.f,0.f};

    #define STAGE(BUF) do{ \
      char* db = smem + (BUF)*16384 + wave*1024; \
      GLL(aP0, db); GLL(aP1, db+4096); GLL(bP0, db+8192); GLL(bP1, db+12288); \
      aP0+=32; aP1+=32; bP0+=32; bP1+=32; }while(0)

    STAGE(0); STAGE(1);
    int bufC = 0, bufS = 2;
    for (int ks=0; ks<nk; ++ks){
      if (ks+2 < nk){
        STAGE(bufS); bufS = bufS==2 ? 0 : bufS+1;
        asm volatile("s_waitcnt vmcnt(8)" ::: "memory");
      } else if (ks+1 < nk){
        asm volatile("s_waitcnt vmcnt(4)" ::: "memory");
      } else {
        asm volatile("s_waitcnt vmcnt(0)" ::: "memory");
      }
      asm volatile("s_barrier" ::: "memory");
      const char* base = smem + bufC*16384;
      bf16x8 af[4], bfv[4];
      #pragma unroll
      for (int q=0;q<4;++q) af[q] = *(const bf16x8*)(base + aRd[q]);
      #pragma unroll
      for (int q=0;q<4;++q) bfv[q] = *(const bf16x8*)(base + bRd[q]);
      #pragma unroll
      for (int mm=0;mm<4;++mm)
        #pragma unroll
        for (int nn=0;nn<4;++nn)
          acc[mm][nn] = __builtin_amdgcn_mfma_f32_16x16x32_bf16(af[mm], bfv[nn], acc[mm][nn], 0,0,0);
      asm volatile("s_waitcnt lgkmcnt(0)" ::: "memory");
      asm volatile("s_barrier" ::: "memory");
      bufC = bufC==2 ? 0 : bufC+1;
    }
    #undef STAGE

    // epilogue
    int colB = xt*128 + wc*64 + (lane&15);
    #pragma unroll
    for (int mm=0;mm<4;++mm){
      #pragma unroll
      for (int j=0;j<4;++j){
        int grow = mt*128 + wr*64 + mm*16 + (lane>>4)*4 + j;
        if (grow >= m) continue;
        size_t gr = (size_t)(rbase + grow);
        #pragma unroll
        for (int nn=0;nn<4;++nn){
          int col = colB + nn*16;
          float val = acc[mm][nn][j];
          if (EPI==0){                                   // rkv split (dense: gr == token row)
            if (col < 1024) g.rbuf[gr*1024+col] = f2bf(sigm(val));
            else if (col < 2048) g.kbuf[gr*1024+col-1024] = f2bf(val);
            else {
              int c2 = col-2048;
              float sg = sigm(g.g_v[c2]);
              float vf = g.v_first[gr*1024+c2];
              g.vbuf[gr*1024+c2] = f2bf(val + (vf-val)*sg);
            }
          } else {                                       // partial write (EPI 1,2)
            g.part[(size_t)ksplit*PSTRIDE + gr*1024 + col] = f2bf(val);
          }
        }
      }
    }
  }
}

// ---------------- merged expert GEMMs (two phases, z-demux, XCD-chunked remap) ----------------
struct MoeArgs {
  const u16* hcat; const u16* htb; const u16* act;
  const u16* wTkr; const u16* wT1; const u16* wTrr; const u16* wTvr; const u16* wT2;
  const int* offs; const int* idx_all;
  u16* actw; u16* part;
};

template<int PHASE>
__global__ __launch_bounds__(256,3) void gemm_moe(MoeArgs g){
  // bijective XCD-chunked remap (T divisible by 8): keeps all xt of one (y,z) on one XCD
  const int T  = (int)(gridDim.x*gridDim.y*gridDim.z);
  const int id = (int)(blockIdx.x + gridDim.x*(blockIdx.y + gridDim.y*blockIdx.z));
  const int work = (id&7)*(T>>3) + (id>>3);
  const int bx = work % (int)gridDim.x;
  const int rest = work / (int)gridDim.x;
  const int by = rest % (int)gridDim.y;
  const int z  = rest / (int)gridDim.y;

  const u16 *Ap, *Bp; long long lda; int K, kdiv, nxt, e, epi;
  if (PHASE==0){
    if (z < 6){ e=z;   Ap=g.hcat; lda=2048; Bp=g.wTkr + (long long)z*4096*1024;     K=1024; kdiv=1024; nxt=32; epi=0; }
    else if (z < 8){ e=z; Ap=g.htb; lda=1024; Bp=g.wT1 + (long long)(z-6)*4096*1024; K=1024; kdiv=1024; nxt=32; epi=1; }
    else { e=z-8; Ap=g.hcat; lda=2048; Bp=g.wTrr + (long long)(z-8)*1024*1024;      K=1024; kdiv=512;  nxt=8;  epi=2; }
  } else {
    if (z < 6){ e=z; Ap=g.act; lda=4096; Bp=g.wTvr + (long long)z*1024*4096;        K=4096; kdiv=2048; nxt=8;  epi=3; }
    else { e=z;     Ap=g.act; lda=4096; Bp=g.wT2 + (long long)(z-6)*1024*4096;      K=4096; kdiv=1024; nxt=8;  epi=4; }
  }
  if (bx >= nxt * (K / kdiv)) return;
  int rbase = g.offs[e], m = g.offs[e+1] - rbase;
  if (by * 128 >= m) return;
  const int xt = bx % nxt;
  const int ksplit = bx / nxt;
  const long long kOff = (long long)ksplit * kdiv;
  __shared__ char smem[49152];
  const int tid = threadIdx.x, lane = tid&63, wave = tid>>6;
  const int wr = wave>>1, wc = wave&1;
  const int nk = kdiv >> 5;

  const int srowi = tid>>2;
  const long long scol = (long long)((((tid&3) ^ ((tid>>3)&3)))*8);

  const u16* bBase0 = Bp + ((long long)(xt*128) + srowi)*(long long)K + kOff + scol;
  const u16* bBase1 = bBase0 + 64ll*(long long)K;

  const int sw = ((lane>>4) ^ ((lane>>1)&3)) << 4;
  int aRd[4], bRd[4];
  #pragma unroll
  for (int q=0;q<4;++q){
    aRd[q] = (wr*64 + q*16 + (lane&15))*64 + sw;
    bRd[q] = 8192 + (wc*64 + q*16 + (lane&15))*64 + sw;
  }

  for (int mt = by; mt*128 < m; mt += gridDim.y){
    const u16 *aP0, *aP1;
    {
      int g0 = mt*128 + srowi;       g0 = g0 < m ? g0 : m-1;
      int g1 = mt*128 + 64 + srowi;  g1 = g1 < m ? g1 : m-1;
      long long r0, r1;
      if (epi <= 2){ r0 = g.idx_all[rbase+g0]; r1 = g.idx_all[rbase+g1]; }
      else { r0 = rbase+g0; r1 = rbase+g1; }
      aP0 = Ap + r0*lda + kOff + scol;
      aP1 = Ap + r1*lda + kOff + scol;
    }
    const u16* bP0 = bBase0;
    const u16* bP1 = bBase1;

    f32x4 acc[4][4];
    #pragma unroll
    for (int mm=0;mm<4;++mm)
      #pragma unroll
      for (int nn=0;nn<4;++nn)
        acc[mm][nn] = f32x4{0.f,0.f,0.f,0.f};

    #define STAGE(BUF) do{ \
      char* db = smem + (BUF)*16384 + wave*1024; \
      GLL(aP0, db); GLL(aP1, db+4096); GLL(bP0, db+8192); GLL(bP1, db+12288); \
      aP0+=32; aP1+=32; bP0+=32; bP1+=32; }while(0)

    STAGE(0); STAGE(1);
    int bufC = 0, bufS = 2;
    for (int ks=0; ks<nk; ++ks){
      if (ks+2 < nk){
        STAGE(bufS); bufS = bufS==2 ? 0 : bufS+1;
        asm volatile("s_waitcnt vmcnt(8)" ::: "memory");
      } else if (ks+1 < nk){
        asm volatile("s_waitcnt vmcnt(4)" ::: "memory");
      } else {
        asm volatile("s_waitcnt vmcnt(0)" ::: "memory");
      }
      asm volatile("s_barrier" ::: "memory");
      const char* base = smem + bufC*16384;
      bf16x8 af[4], bfv[4];
      #pragma unroll
      for (int q=0;q<4;++q) af[q] = *(const bf16x8*)(base + aRd[q]);
      #pragma unroll
      for (int q=0;q<4;++q) bfv[q] = *(const bf16x8*)(base + bRd[q]);
      #pragma unroll
      for (int mm=0;mm<4;++mm)
        #pragma unroll
        for (int nn=0;nn<4;++nn)
          acc[mm][nn] = __builtin_amdgcn_mfma_f32_16x16x32_bf16(af[mm], bfv[nn], acc[mm][nn], 0,0,0);
      asm volatile("s_waitcnt lgkmcnt(0)" ::: "memory");
      asm volatile("s_barrier" ::: "memory");
      bufC = bufC==2 ? 0 : bufC+1;
    }
    #undef STAGE

    int colB = xt*128 + wc*64 + (lane&15);
    #pragma unroll
    for (int mm=0;mm<4;++mm){
      #pragma unroll
      for (int j=0;j<4;++j){
        int grow = mt*128 + wr*64 + mm*16 + (lane>>4)*4 + j;
        if (grow >= m) continue;
        size_t gr = (size_t)(rbase + grow);
        #pragma unroll
        for (int nn=0;nn<4;++nn){
          int col = colB + nn*16;
          float val = acc[mm][nn][j];
          if (epi == 0){                        // relu^2 -> act
            float r_ = fmaxf(val, 0.f);
            g.actw[gr*4096+col] = f2bf(r_*r_);
          } else if (epi == 1){                 // gelu -> act
            float t3 = val*val*val;
            float th = tanhf(0.79788456080286535588f*(val + 0.044715f*t3));
            g.actw[gr*4096+col] = f2bf(0.5f*val*(1.f+th));
          } else if (epi == 2){                 // rec partials, slots 2,3
            g.part[(size_t)(2+ksplit)*PSTRIDE + gr*1024 + col] = f2bf(val);
          } else {                              // expert-out partials, slots 0..3
            g.part[(size_t)ksplit*PSTRIDE + gr*1024 + col] = f2bf(val);
          }
        }
      }
    }
  }
}

// ---------------- reduce kernels ----------------
__global__ void red_ht(const u16* __restrict__ hcat, const u16* __restrict__ part,
                       const float* __restrict__ bb, u16* __restrict__ ht){
  int c = threadIdx.x*4;
  size_t i = (size_t)blockIdx.x*1024 + c;
  U16x4 p0 = *(const U16x4*)(part + i);
  U16x4 p1 = *(const U16x4*)(part + PSTRIDE + i);
  U16x4 hv = *(const U16x4*)(hcat + (size_t)blockIdx.x*2048 + c);
  U16x4 o;
  #pragma unroll
  for (int j=0;j<4;++j) o.v[j] = f2bf(bf2f(hv.v[j]) + bf2f(p0.v[j]) + bf2f(p1.v[j]) + bb[c+j]);
  *(U16x4*)(ht + i) = o;
}
// experts combine: rwkv rows: 0.5*sigm(p2+p3)*(p0+p1); trans rows: 0.5*(p0+p1+p2+p3)
__global__ void red_moe(const int* __restrict__ offs, const int* __restrict__ idx_all,
                        const u16* __restrict__ part, float* __restrict__ out){
  int gr = blockIdx.x;
  if (gr >= offs[8]) return;
  int tok = idx_all[gr];
  bool isr = gr < offs[6];
  int c = threadIdx.x*4;
  size_t i = (size_t)gr*1024 + c;
  U16x4 p0 = *(const U16x4*)(part + i);
  U16x4 p1 = *(const U16x4*)(part + PSTRIDE + i);
  U16x4 p2 = *(const U16x4*)(part + 2*PSTRIDE + i);
  U16x4 p3 = *(const U16x4*)(part + 3*PSTRIDE + i);
  #pragma unroll
  for (int j=0;j<4;++j){
    float v;
    if (isr){
      float rc = sigm(bf2f(p2.v[j]) + bf2f(p3.v[j]));
      v = 0.5f*(bf2f(p0.v[j]) + bf2f(p1.v[j]))*rc;
    } else {
      v = 0.5f*(bf2f(p0.v[j]) + bf2f(p1.v[j]) + bf2f(p2.v[j]) + bf2f(p3.v[j]));
    }
    atomicAdd(&out[(size_t)tok*1024 + c + j], v);
  }
}

// ---------------- host launch ----------------
extern "C" void kernel_launch(void* const* d_in, const int* in_sizes, int n_in,
                              void* d_out, int out_size, void* d_ws, size_t ws_size,
                              hipStream_t stream) {
  const float* x       = (const float*)d_in[0];
  const float* v_first = (const float*)d_in[1];
  const int*   winners = (const int*)d_in[2];
  const float* ln1_g   = (const float*)d_in[4];
  const float* ln1_b   = (const float*)d_in[5];
  const float* ln2_g   = (const float*)d_in[6];
  const float* ln2_b   = (const float*)d_in[7];
  const float* Wr      = (const float*)d_in[8];
  const float* Wk      = (const float*)d_in[9];
  const float* Wv      = (const float*)d_in[10];
  const float* Wo      = (const float*)d_in[11];
  const float* w_decay = (const float*)d_in[12];
  const float* g_v     = (const float*)d_in[13];
  const float* Wb      = (const float*)d_in[14];
  const float* bb      = (const float*)d_in[15];
  const float* Wk_r    = (const float*)d_in[16];
  const float* Wv_r    = (const float*)d_in[17];
  const float* Wr_r    = (const float*)d_in[18];
  const float* W1_t    = (const float*)d_in[19];
  const float* W2_t    = (const float*)d_in[20];
  float* out = (float*)d_out;

  char* p = (char*)d_ws;
  auto alloc = [&](size_t bytes)->char*{ char* r=p; p += (bytes+255)&~(size_t)255; return r; };
  u16* wTrkv = (u16*)alloc(3072ull*1024*2);
  u16* wTo   = (u16*)alloc(1024ull*1024*2);
  u16* wTb   = (u16*)alloc(1024ull*2048*2);
  u16* wTkr  = (u16*)alloc(6ull*4096*1024*2);
  u16* wTvr  = (u16*)alloc(6ull*1024*4096*2);
  u16* wTrr  = (u16*)alloc(6ull*1024*1024*2);
  u16* wT1   = (u16*)alloc(2ull*4096*1024*2);
  u16* wT2   = (u16*)alloc(2ull*1024*4096*2);
  u16* h1    = (u16*)alloc(4096ull*1024*2);
  u16* rbuf  = (u16*)alloc(4096ull*1024*2);
  u16* kbuf  = (u16*)alloc(4096ull*1024*2);
  u16* vbuf  = (u16*)alloc(4096ull*1024*2);
  u16* rsb   = (u16*)alloc(4096ull*1024*2);
  u16* hcat  = (u16*)alloc(4096ull*2048*2);
  u16* htb   = (u16*)alloc(4096ull*1024*2);
  u16* act   = (u16*)alloc(8192ull*4096*2);
  u16* partial = (u16*)alloc(4ull*8192*1024*2);
  float* carry  = (float*)alloc(2ull*32*1024*4);
  float* startv = (float*)alloc(2ull*32*1024*4);
  int* offs   = (int*)alloc(16*4);
  int* cursor = (int*)alloc(8*4);
  int* idx_all= (int*)alloc(8192*4);

  dim3 B256(256);

  // ---- merged weight transpose-convert (one dispatch, 128x64 tiles) ----
  {
    CJobs cj; int base = 0, ji = 0;
    auto add = [&](const float* s, u16* d, int K, int N){
      cj.j[ji++] = CJob{s, d, K, N, base}; base += (K>>7)*(N>>6);
    };
    add(Wr, wTrkv, 1024,1024); add(Wk, wTrkv+1024*1024, 1024,1024);
    add(Wv, wTrkv+2048*1024, 1024,1024); add(Wo, wTo, 1024,1024);
    add(Wb, wTb, 2048,1024);
    for (int e2=0;e2<6;++e2) add(Wk_r + (size_t)e2*1024*4096, wTkr + (size_t)e2*4096*1024, 1024,4096);
    for (int e2=0;e2<6;++e2) add(Wv_r + (size_t)e2*4096*1024, wTvr + (size_t)e2*1024*4096, 4096,1024);
    for (int e2=0;e2<6;++e2) add(Wr_r + (size_t)e2*1024*1024, wTrr + (size_t)e2*1024*1024, 1024,1024);
    for (int e2=0;e2<2;++e2) add(W1_t + (size_t)e2*1024*4096, wT1 + (size_t)e2*4096*1024, 1024,4096);
    for (int e2=0;e2<2;++e2) add(W2_t + (size_t)e2*4096*1024, wT2 + (size_t)e2*1024*4096, 4096,1024);
    conv_all<<<dim3(base,1,1),B256,0,stream>>>(cj);
  }

  // routing
  route_count<<<1,B256,0,stream>>>(winners, offs, cursor);
  route_scatter<<<32,B256,0,stream>>>(winners, offs, cursor, idx_all);

  // LN1 -> h1
  ln_k<<<4096,B256,0,stream>>>(x, ln1_g, ln1_b, h1, 1024);

  // r|k|v = h1 @ [Wr|Wk|Wv]
  {
    GArgs ga{}; ga.A=h1; ga.B=wTrkv; ga.lda=1024; ga.K=1024; ga.Mdense=4096; ga.nxt=24; ga.kdiv=1024;
    ga.v_first=v_first; ga.g_v=g_v; ga.rbuf=rbuf; ga.kbuf=kbuf; ga.vbuf=vbuf;
    gemm_k<0,0><<<dim3(24,32,1),B256,0,stream>>>(ga);
  }

  // scan
  scan_p1<<<dim3(4,32,2),B256,0,stream>>>(kbuf, vbuf, w_decay, carry);
  scan_p2<<<dim3(4,2,1), B256,0,stream>>>(w_decay, carry, startv);
  scan_p3<<<dim3(4,32,2),B256,0,stream>>>(kbuf, vbuf, rbuf, w_decay, startv, rsb, hcat);

  // attout partials (split-K 2) + fused reduce+LN2: out = x+attout, hcat[:, :1024] = LN(out)
  {
    GArgs ga{}; ga.A=rsb; ga.B=wTo; ga.lda=1024; ga.K=1024; ga.Mdense=4096; ga.nxt=8; ga.kdiv=512;
    ga.part=partial;
    gemm_k<1,0><<<dim3(16,32,1),B256,0,stream>>>(ga);
  }
  red_x_ln<<<4096,B256,0,stream>>>(x, partial, ln2_g, ln2_b, out, hcat);

  // bridge partials (split-K 2) + reduce: ht = h + bridge + bb
  {
    GArgs ga{}; ga.A=hcat; ga.B=wTb; ga.lda=2048; ga.K=2048; ga.Mdense=4096; ga.nxt=8; ga.kdiv=1024;
    ga.part=partial;
    gemm_k<2,0><<<dim3(16,32,1),B256,0,stream>>>(ga);
  }
  red_ht<<<4096,B256,0,stream>>>(hcat, partial, bb, htb);

  // merged expert phase A: relu^2(hcat@Wk_r) x6 | gelu(htb@W1) x2 | rec partials x6
  {
    MoeArgs ma{};
    ma.hcat=hcat; ma.htb=htb; ma.act=act;
    ma.wTkr=wTkr; ma.wT1=wT1; ma.wTrr=wTrr; ma.wTvr=wTvr; ma.wT2=wT2;
    ma.offs=offs; ma.idx_all=idx_all; ma.actw=act; ma.part=partial;
    gemm_moe<0><<<dim3(32,6,14),B256,0,stream>>>(ma);
    // merged expert phase B: (act@Wv_r) x6 split2 | (act@W2) x2 split4
    gemm_moe<1><<<dim3(32,6,8),B256,0,stream>>>(ma);
  }
  // combine experts into out
  red_moe<<<8192,B256,0,stream>>>(offs, idx_all, partial, out);

  (void)in_sizes; (void)n_in; (void)out_size; (void)ws_size;
}

// Round 12
// 706.820 us; speedup vs baseline: 1.0598x; 1.0082x over previous
//
#include <hip/hip_runtime.h>

typedef unsigned short u16;
typedef __bf16 bf16x8 __attribute__((ext_vector_type(8)));
typedef float f32x4 __attribute__((ext_vector_type(4)));

__device__ __forceinline__ float bf2f(u16 u){ union{unsigned i;float f;}x; x.i=((unsigned)u)<<16; return x.f; }
__device__ __forceinline__ u16 f2bf(float f){ union{float f;unsigned i;}x; x.f=f; unsigned r = x.i + 0x7FFFu + ((x.i>>16)&1u); return (u16)(r>>16); }
__device__ __forceinline__ float sigm(float x){ return 1.f/(1.f+expf(-x)); }

struct __align__(8) U16x4 { u16 v[4]; };

#define PSTRIDE 8388608ull   // elems per split in partial buffer [4][8192][1024]

// ---------------- f32 [K][N] -> bf16 [N][K] transpose-convert (shared tile body) ----------------
struct CJob { const float* src; u16* dst; int K, N, base; };
struct CJobs { CJob j[27]; };

__device__ __forceinline__ void conv_tile(const CJobs& cj, int id, u16 (*tile)[65]){
  int sel = 0;
  #pragma unroll
  for (int i=1;i<27;++i) if (cj.j[i].base <= id) sel = i;
  const float* __restrict__ src = cj.j[sel].src;
  u16* __restrict__ dst = cj.j[sel].dst;
  int K = cj.j[sel].K, N = cj.j[sel].N;
  int lt = id - cj.j[sel].base;
  int tn = N >> 6;
  int k0 = (lt / tn) * 128, n0 = (lt % tn) * 64;
  int tid = threadIdx.x;
  #pragma unroll
  for (int it=0; it<8; ++it){
    int e = it*1024 + tid*4;
    int r = e>>6, c = e&63;
    float4 v = *(const float4*)(src + (size_t)(k0+r)*N + n0 + c);
    tile[r][c+0]=f2bf(v.x); tile[r][c+1]=f2bf(v.y); tile[r][c+2]=f2bf(v.z); tile[r][c+3]=f2bf(v.w);
  }
  __syncthreads();
  #pragma unroll
  for (int it=0; it<8; ++it){
    int e = it*1024 + tid*4;
    int n = e>>7, k = e&127;
    U16x4 o;
    #pragma unroll
    for (int j=0;j<4;++j) o.v[j] = tile[k+j][n];
    *(U16x4*)(dst + (size_t)(n0+n)*K + k0 + k) = o;
  }
}

__global__ void conv_all(CJobs cj){
  __shared__ u16 tile[128][65];
  conv_tile(cj, blockIdx.x, tile);
}

// ---------------- LayerNorm: f32 [4096][1024] -> bf16 rows (stride ostride) ----------------
__global__ void ln_k(const float* __restrict__ x, const float* __restrict__ g, const float* __restrict__ b,
                     u16* __restrict__ out, int ostride){
  int row = blockIdx.x, tid = threadIdx.x;
  float4 v = *(const float4*)(x + (size_t)row*1024 + tid*4);
  float s = v.x+v.y+v.z+v.w;
  float ss = v.x*v.x+v.y*v.y+v.z*v.z+v.w*v.w;
  #pragma unroll
  for (int o=32;o;o>>=1){ s += __shfl_down(s,o); ss += __shfl_down(ss,o); }
  __shared__ float sm[8];
  int lane = tid&63, wv = tid>>6;
  if (!lane){ sm[wv]=s; sm[4+wv]=ss; }
  __syncthreads();
  s = sm[0]+sm[1]+sm[2]+sm[3]; ss = sm[4]+sm[5]+sm[6]+sm[7];
  float mean = s*(1.f/1024.f);
  float var = ss*(1.f/1024.f) - mean*mean;
  float inv = rsqrtf(var + 1e-5f);
  U16x4 o;
  const float* vp = &v.x;
  #pragma unroll
  for (int j=0;j<4;++j){
    int c = tid*4+j;
    o.v[j] = f2bf((vp[j]-mean)*inv*g[c] + b[c]);
  }
  *(U16x4*)(out + (size_t)row*ostride + tid*4) = o;
}

// ---------------- fused: out = x + p0 + p1 ; hcat[:, :1024] = LN(out) ----------------
__global__ void red_x_ln(const float* __restrict__ x, const u16* __restrict__ part,
                         const float* __restrict__ g, const float* __restrict__ b,
                         float* __restrict__ out, u16* __restrict__ hcat){
  int row = blockIdx.x, tid = threadIdx.x;
  size_t i = (size_t)row*1024 + tid*4;
  U16x4 p0 = *(const U16x4*)(part + i);
  U16x4 p1 = *(const U16x4*)(part + PSTRIDE + i);
  float4 xv = *(const float4*)(x + i);
  float4 v;
  v.x = xv.x + bf2f(p0.v[0]) + bf2f(p1.v[0]);
  v.y = xv.y + bf2f(p0.v[1]) + bf2f(p1.v[1]);
  v.z = xv.z + bf2f(p0.v[2]) + bf2f(p1.v[2]);
  v.w = xv.w + bf2f(p0.v[3]) + bf2f(p1.v[3]);
  *(float4*)(out + i) = v;
  float s = v.x+v.y+v.z+v.w;
  float ss = v.x*v.x+v.y*v.y+v.z*v.z+v.w*v.w;
  #pragma unroll
  for (int o=32;o;o>>=1){ s += __shfl_down(s,o); ss += __shfl_down(ss,o); }
  __shared__ float sm[8];
  int lane = tid&63, wv = tid>>6;
  if (!lane){ sm[wv]=s; sm[4+wv]=ss; }
  __syncthreads();
  s = sm[0]+sm[1]+sm[2]+sm[3]; ss = sm[4]+sm[5]+sm[6]+sm[7];
  float mean = s*(1.f/1024.f);
  float var = ss*(1.f/1024.f) - mean*mean;
  float inv = rsqrtf(var + 1e-5f);
  U16x4 o;
  const float* vp = &v.x;
  #pragma unroll
  for (int j=0;j<4;++j){
    int c = tid*4+j;
    o.v[j] = f2bf((vp[j]-mean)*inv*g[c] + b[c]);
  }
  *(U16x4*)(hcat + (size_t)row*2048 + tid*4) = o;
}

// ---------------- 3-phase chunked linear scan (p1 & p3 host expert-weight conv) ----------------
__global__ void scan1_conv(const u16* __restrict__ kbuf, const u16* __restrict__ vbuf,
                           const float* __restrict__ w_decay, float* __restrict__ carry, CJobs cj){
  __shared__ u16 tile[128][65];
  int id = blockIdx.x;
  if (id < 256){
    int c = (id&3)*256 + threadIdx.x;
    int chunk = (id>>2)&31, b = id>>7;
    float w = sigm(w_decay[c]);
    float s = 0.f;
    size_t idx = ((size_t)(b*2048 + chunk*64))*1024 + c;
    #pragma unroll 4
    for (int i=0;i<64;++i){ s = w*s + bf2f(kbuf[idx])*bf2f(vbuf[idx]); idx += 1024; }
    carry[((size_t)(b*32+chunk))*1024 + c] = s;
    return;
  }
  conv_tile(cj, id - 256, tile);
}
__global__ void scan_p2(const float* __restrict__ w_decay, const float* __restrict__ carry,
                        float* __restrict__ startv){
  int c = blockIdx.x*256 + threadIdx.x;
  int b = blockIdx.y;
  float w = sigm(w_decay[c]);
  float wL = w;
  #pragma unroll
  for (int i=0;i<6;++i) wL *= wL;   // w^64
  float p = 0.f;
  for (int j=0;j<32;++j){
    size_t id = ((size_t)(b*32+j))*1024 + c;
    startv[id] = p;
    p = wL*p + carry[id];
  }
}
__global__ void scan3_conv(const u16* __restrict__ kbuf, const u16* __restrict__ vbuf, const u16* __restrict__ rbuf,
                           const float* __restrict__ w_decay, const float* __restrict__ startv,
                           u16* __restrict__ rs, u16* __restrict__ hcat, CJobs cj){
  __shared__ u16 tile[128][65];
  int id = blockIdx.x;
  if (id < 256){
    int c = (id&3)*256 + threadIdx.x;
    int chunk = (id>>2)&31, b = id>>7;
    float w = sigm(w_decay[c]);
    float s = startv[((size_t)(b*32+chunk))*1024 + c];
    size_t t0 = (size_t)b*2048 + chunk*64;
    size_t idx = t0*1024 + c;
    size_t idx2 = t0*2048 + 1024 + c;
    for (int i=0;i<64;++i){
      s = w*s + bf2f(kbuf[idx])*bf2f(vbuf[idx]);
      rs[idx] = f2bf(bf2f(rbuf[idx]) * s);
      hcat[idx2] = f2bf(s);
      idx += 1024; idx2 += 2048;
    }
    return;
  }
  conv_tile(cj, id - 256, tile);
}

// ---------------- routing ----------------
__global__ void route_count(const int* __restrict__ winners, int* __restrict__ offs, int* __restrict__ cursor){
  __shared__ int cnt[8];
  if (threadIdx.x < 8) cnt[threadIdx.x] = 0;
  __syncthreads();
  for (int p = threadIdx.x; p < 8192; p += 256) atomicAdd(&cnt[winners[p]&7], 1);
  __syncthreads();
  if (threadIdx.x == 0){
    int s = 0;
    #pragma unroll
    for (int e=0;e<8;++e){ offs[e]=s; s+=cnt[e]; }
    offs[8]=s;
  }
  if (threadIdx.x < 8) cursor[threadIdx.x] = 0;
}
__global__ void route_scatter(const int* __restrict__ winners, const int* __restrict__ offs,
                              int* __restrict__ cursor, int* __restrict__ idx_all){
  int p = blockIdx.x*256 + threadIdx.x;
  if (p < 8192){
    int e = winners[p]&7;
    int pos = offs[e] + atomicAdd(&cursor[e], 1);
    idx_all[pos] = p>>1;
  }
}

// LDS slot swizzle (both-sides XOR, GLL dest stays linear):
//   writer lane l sources global slot ((l&3)^((l>>3)&3)); reader uses slot ((lane>>4)^((lane>>1)&3)).

// ---------------- universal 128x128 bf16 MFMA GEMM: BK=32, ring-3, depth-2 prefetch ----------------
struct GArgs {
  const u16* A; const u16* B;
  long long lda, bstride;
  int K, Mdense, eBase, nxt, kdiv;
  const int* offs; const int* idx_all;
  const float* v_first; const float* g_v;
  u16* rbuf; u16* kbuf; u16* vbuf;
  u16* act; u16* part;
};

#define GLL(gp, lp) __builtin_amdgcn_global_load_lds((const __attribute__((address_space(1))) void*)(gp), \
                                                     (__attribute__((address_space(3))) void*)(lp), 16, 0, 0)

template<int EPI, int GATHER>
__global__ __launch_bounds__(256,3) void gemm_k(GArgs g){
  int e = g.eBase + blockIdx.z;
  int rbase = 0, m = g.Mdense;
  if (g.offs){ rbase = g.offs[e]; m = g.offs[e+1] - rbase; }
  if ((int)blockIdx.y * 128 >= m) return;
  const int xt = (int)blockIdx.x % g.nxt;
  const int ksplit = (int)blockIdx.x / g.nxt;
  const long long kOff = (long long)ksplit * g.kdiv;
  __shared__ char smem[49152];          // 3 bufs x (A[128][32] 8KB + B[128][32] 8KB)
  const int tid = threadIdx.x, lane = tid&63, wave = tid>>6;
  const int wr = wave>>1, wc = wave&1;
  const int nk = g.kdiv >> 5;

  const int srowi = tid>>2;             // 0..63
  const long long scol = (long long)((((tid&3) ^ ((tid>>3)&3)))*8);   // pre-swizzled source slot

  const u16* bBase0 = g.B + (long long)blockIdx.z*g.bstride
                    + ((long long)(xt*128) + srowi)*(long long)g.K + kOff + scol;
  const u16* bBase1 = bBase0 + 64ll*(long long)g.K;

  const int sw = ((lane>>4) ^ ((lane>>1)&3)) << 4;                    // swizzled read slot (bytes)
  int aRd[4], bRd[4];
  #pragma unroll
  for (int q=0;q<4;++q){
    aRd[q] = (wr*64 + q*16 + (lane&15))*64 + sw;
    bRd[q] = 8192 + (wc*64 + q*16 + (lane&15))*64 + sw;
  }

  for (int mt = blockIdx.y; mt*128 < m; mt += gridDim.y){
    const u16 *aP0, *aP1;
    {
      int g0 = mt*128 + srowi;       g0 = g0 < m ? g0 : m-1;
      int g1 = mt*128 + 64 + srowi;  g1 = g1 < m ? g1 : m-1;
      long long r0, r1;
      if (GATHER){ r0 = g.idx_all[rbase+g0]; r1 = g.idx_all[rbase+g1]; }
      else if (g.offs){ r0 = rbase+g0; r1 = rbase+g1; }
      else { r0 = g0; r1 = g1; }
      aP0 = g.A + r0*g.lda + kOff + scol;
      aP1 = g.A + r1*g.lda + kOff + scol;
    }
    const u16* bP0 = bBase0;
    const u16* bP1 = bBase1;

    f32x4 acc[4][4];
    #pragma unroll
    for (int mm=0;mm<4;++mm)
      #pragma unroll
      for (int nn=0;nn<4;++nn)
        acc[mm][nn] = f32x4{0.f,0.f,0.f,0.f};

    #define STAGE(BUF) do{ \
      char* db = smem + (BUF)*16384 + wave*1024; \
      GLL(aP0, db); GLL(aP1, db+4096); GLL(bP0, db+8192); GLL(bP1, db+12288); \
      aP0+=32; aP1+=32; bP0+=32; bP1+=32; }while(0)

    STAGE(0); STAGE(1);
    int bufC = 0, bufS = 2;
    for (int ks=0; ks<nk; ++ks){
      if (ks+2 < nk){
        STAGE(bufS); bufS = bufS==2 ? 0 : bufS+1;
        asm volatile("s_waitcnt vmcnt(8)" ::: "memory");
      } else if (ks+1 < nk){
        asm volatile("s_waitcnt vmcnt(4)" ::: "memory");
      } else {
        asm volatile("s_waitcnt vmcnt(0)" ::: "memory");
      }
      asm volatile("s_barrier" ::: "memory");
      const char* base = smem + bufC*16384;
      bf16x8 af[4], bfv[4];
      #pragma unroll
      for (int q=0;q<4;++q) af[q] = *(const bf16x8*)(base + aRd[q]);
      #pragma unroll
      for (int q=0;q<4;++q) bfv[q] = *(const bf16x8*)(base + bRd[q]);
      #pragma unroll
      for (int mm=0;mm<4;++mm)
        #pragma unroll
        for (int nn=0;nn<4;++nn)
          acc[mm][nn] = __builtin_amdgcn_mfma_f32_16x16x32_bf16(af[mm], bfv[nn], acc[mm][nn], 0,0,0);
      asm volatile("s_waitcnt lgkmcnt(0)" ::: "memory");
      asm volatile("s_barrier" ::: "memory");
      bufC = bufC==2 ? 0 : bufC+1;
    }
    #undef STAGE

    // epilogue
    int colB = xt*128 + wc*64 + (lane&15);
    #pragma unroll
    for (int mm=0;mm<4;++mm){
      #pragma unroll
      for (int j=0;j<4;++j){
        int grow = mt*128 + wr*64 + mm*16 + (lane>>4)*4 + j;
        if (grow >= m) continue;
        size_t gr = (size_t)(rbase + grow);
        #pragma unroll
        for (int nn=0;nn<4;++nn){
          int col = colB + nn*16;
          float val = acc[mm][nn][j];
          if (EPI==0){                                   // rkv split (dense: gr == token row)
            if (col < 1024) g.rbuf[gr*1024+col] = f2bf(sigm(val));
            else if (col < 2048) g.kbuf[gr*1024+col-1024] = f2bf(val);
            else {
              int c2 = col-2048;
              float sg = sigm(g.g_v[c2]);
              float vf = g.v_first[gr*1024+c2];
              g.vbuf[gr*1024+c2] = f2bf(val + (vf-val)*sg);
            }
          } else {                                       // partial write (EPI 1,2)
            g.part[(size_t)ksplit*PSTRIDE + gr*1024 + col] = f2bf(val);
          }
        }
      }
    }
  }
}

// ---------------- merged expert GEMMs (two phases, z-demux, XCD-chunked remap) ----------------
struct MoeArgs {
  const u16* hcat; const u16* htb; const u16* act;
  const u16* wTkr; const u16* wT1; const u16* wTrr; const u16* wTvr; const u16* wT2;
  const int* offs; const int* idx_all;
  u16* actw; u16* part;
};

template<int PHASE>
__global__ __launch_bounds__(256,3) void gemm_moe(MoeArgs g){
  // bijective XCD-chunked remap (T divisible by 8)
  const int T  = (int)(gridDim.x*gridDim.y*gridDim.z);
  const int id = (int)(blockIdx.x + gridDim.x*(blockIdx.y + gridDim.y*blockIdx.z));
  const int work = (id&7)*(T>>3) + (id>>3);
  const int bx = work % (int)gridDim.x;
  const int rest = work / (int)gridDim.x;
  const int by = rest % (int)gridDim.y;
  const int z  = rest / (int)gridDim.y;

  const u16 *Ap, *Bp; long long lda; int K, kdiv, nxt, e, epi;
  if (PHASE==0){
    if (z < 6){ e=z;   Ap=g.hcat; lda=2048; Bp=g.wTkr + (long long)z*4096*1024;     K=1024; kdiv=1024; nxt=32; epi=0; }
    else if (z < 8){ e=z; Ap=g.htb; lda=1024; Bp=g.wT1 + (long long)(z-6)*4096*1024; K=1024; kdiv=1024; nxt=32; epi=1; }
    else { e=z-8; Ap=g.hcat; lda=2048; Bp=g.wTrr + (long long)(z-8)*1024*1024;      K=1024; kdiv=512;  nxt=8;  epi=2; }
  } else {
    if (z < 6){ e=z; Ap=g.act; lda=4096; Bp=g.wTvr + (long long)z*1024*4096;        K=4096; kdiv=2048; nxt=8;  epi=3; }
    else { e=z;     Ap=g.act; lda=4096; Bp=g.wT2 + (long long)(z-6)*1024*4096;      K=4096; kdiv=1024; nxt=8;  epi=4; }
  }
  if (bx >= nxt * (K / kdiv)) return;
  int rbase = g.offs[e], m = g.offs[e+1] - rbase;
  if (by * 128 >= m) return;
  const int xt = bx % nxt;
  const int ksplit = bx / nxt;
  const long long kOff = (long long)ksplit * kdiv;
  __shared__ char smem[49152];
  const int tid = threadIdx.x, lane = tid&63, wave = tid>>6;
  const int wr = wave>>1, wc = wave&1;
  const int nk = kdiv >> 5;

  const int srowi = tid>>2;
  const long long scol = (long long)((((tid&3) ^ ((tid>>3)&3)))*8);

  const u16* bBase0 = Bp + ((long long)(xt*128) + srowi)*(long long)K + kOff + scol;
  const u16* bBase1 = bBase0 + 64ll*(long long)K;

  const int sw = ((lane>>4) ^ ((lane>>1)&3)) << 4;
  int aRd[4], bRd[4];
  #pragma unroll
  for (int q=0;q<4;++q){
    aRd[q] = (wr*64 + q*16 + (lane&15))*64 + sw;
    bRd[q] = 8192 + (wc*64 + q*16 + (lane&15))*64 + sw;
  }

  for (int mt = by; mt*128 < m; mt += gridDim.y){
    const u16 *aP0, *aP1;
    {
      int g0 = mt*128 + srowi;       g0 = g0 < m ? g0 : m-1;
      int g1 = mt*128 + 64 + srowi;  g1 = g1 < m ? g1 : m-1;
      long long r0, r1;
      if (epi <= 2){ r0 = g.idx_all[rbase+g0]; r1 = g.idx_all[rbase+g1]; }
      else { r0 = rbase+g0; r1 = rbase+g1; }
      aP0 = Ap + r0*lda + kOff + scol;
      aP1 = Ap + r1*lda + kOff + scol;
    }
    const u16* bP0 = bBase0;
    const u16* bP1 = bBase1;

    f32x4 acc[4][4];
    #pragma unroll
    for (int mm=0;mm<4;++mm)
      #pragma unroll
      for (int nn=0;nn<4;++nn)
        acc[mm][nn] = f32x4{0.f,0.f,0.f,0.f};

    #define STAGE(BUF) do{ \
      char* db = smem + (BUF)*16384 + wave*1024; \
      GLL(aP0, db); GLL(aP1, db+4096); GLL(bP0, db+8192); GLL(bP1, db+12288); \
      aP0+=32; aP1+=32; bP0+=32; bP1+=32; }while(0)

    STAGE(0); STAGE(1);
    int bufC = 0, bufS = 2;
    for (int ks=0; ks<nk; ++ks){
      if (ks+2 < nk){
        STAGE(bufS); bufS = bufS==2 ? 0 : bufS+1;
        asm volatile("s_waitcnt vmcnt(8)" ::: "memory");
      } else if (ks+1 < nk){
        asm volatile("s_waitcnt vmcnt(4)" ::: "memory");
      } else {
        asm volatile("s_waitcnt vmcnt(0)" ::: "memory");
      }
      asm volatile("s_barrier" ::: "memory");
      const char* base = smem + bufC*16384;
      bf16x8 af[4], bfv[4];
      #pragma unroll
      for (int q=0;q<4;++q) af[q] = *(const bf16x8*)(base + aRd[q]);
      #pragma unroll
      for (int q=0;q<4;++q) bfv[q] = *(const bf16x8*)(base + bRd[q]);
      #pragma unroll
      for (int mm=0;mm<4;++mm)
        #pragma unroll
        for (int nn=0;nn<4;++nn)
          acc[mm][nn] = __builtin_amdgcn_mfma_f32_16x16x32_bf16(af[mm], bfv[nn], acc[mm][nn], 0,0,0);
      asm volatile("s_waitcnt lgkmcnt(0)" ::: "memory");
      asm volatile("s_barrier" ::: "memory");
      bufC = bufC==2 ? 0 : bufC+1;
    }
    #undef STAGE

    int colB = xt*128 + wc*64 + (lane&15);
    #pragma unroll
    for (int mm=0;mm<4;++mm){
      #pragma unroll
      for (int j=0;j<4;++j){
        int grow = mt*128 + wr*64 + mm*16 + (lane>>4)*4 + j;
        if (grow >= m) continue;
        size_t gr = (size_t)(rbase + grow);
        #pragma unroll
        for (int nn=0;nn<4;++nn){
          int col = colB + nn*16;
          float val = acc[mm][nn][j];
          if (epi == 0){                        // relu^2 -> act
            float r_ = fmaxf(val, 0.f);
            g.actw[gr*4096+col] = f2bf(r_*r_);
          } else if (epi == 1){                 // gelu -> act
            float t3 = val*val*val;
            float th = tanhf(0.79788456080286535588f*(val + 0.044715f*t3));
            g.actw[gr*4096+col] = f2bf(0.5f*val*(1.f+th));
          } else if (epi == 2){                 // rec partials, slots 2,3
            g.part[(size_t)(2+ksplit)*PSTRIDE + gr*1024 + col] = f2bf(val);
          } else {                              // expert-out partials, slots 0..3
            g.part[(size_t)ksplit*PSTRIDE + gr*1024 + col] = f2bf(val);
          }
        }
      }
    }
  }
}

// ---------------- reduce kernels ----------------
__global__ void red_ht(const u16* __restrict__ hcat, const u16* __restrict__ part,
                       const float* __restrict__ bb, u16* __restrict__ ht){
  int c = threadIdx.x*4;
  size_t i = (size_t)blockIdx.x*1024 + c;
  U16x4 p0 = *(const U16x4*)(part + i);
  U16x4 p1 = *(const U16x4*)(part + PSTRIDE + i);
  U16x4 hv = *(const U16x4*)(hcat + (size_t)blockIdx.x*2048 + c);
  U16x4 o;
  #pragma unroll
  for (int j=0;j<4;++j) o.v[j] = f2bf(bf2f(hv.v[j]) + bf2f(p0.v[j]) + bf2f(p1.v[j]) + bb[c+j]);
  *(U16x4*)(ht + i) = o;
}
// experts combine: rwkv rows: 0.5*sigm(p2+p3)*(p0+p1); trans rows: 0.5*(p0+p1+p2+p3)
__global__ void red_moe(const int* __restrict__ offs, const int* __restrict__ idx_all,
                        const u16* __restrict__ part, float* __restrict__ out){
  int gr = blockIdx.x;
  if (gr >= offs[8]) return;
  int tok = idx_all[gr];
  bool isr = gr < offs[6];
  int c = threadIdx.x*4;
  size_t i = (size_t)gr*1024 + c;
  U16x4 p0 = *(const U16x4*)(part + i);
  U16x4 p1 = *(const U16x4*)(part + PSTRIDE + i);
  U16x4 p2 = *(const U16x4*)(part + 2*PSTRIDE + i);
  U16x4 p3 = *(const U16x4*)(part + 3*PSTRIDE + i);
  #pragma unroll
  for (int j=0;j<4;++j){
    float v;
    if (isr){
      float rc = sigm(bf2f(p2.v[j]) + bf2f(p3.v[j]));
      v = 0.5f*(bf2f(p0.v[j]) + bf2f(p1.v[j]))*rc;
    } else {
      v = 0.5f*(bf2f(p0.v[j]) + bf2f(p1.v[j]) + bf2f(p2.v[j]) + bf2f(p3.v[j]));
    }
    atomicAdd(&out[(size_t)tok*1024 + c + j], v);
  }
}

// ---------------- host launch ----------------
extern "C" void kernel_launch(void* const* d_in, const int* in_sizes, int n_in,
                              void* d_out, int out_size, void* d_ws, size_t ws_size,
                              hipStream_t stream) {
  const float* x       = (const float*)d_in[0];
  const float* v_first = (const float*)d_in[1];
  const int*   winners = (const int*)d_in[2];
  const float* ln1_g   = (const float*)d_in[4];
  const float* ln1_b   = (const float*)d_in[5];
  const float* ln2_g   = (const float*)d_in[6];
  const float* ln2_b   = (const float*)d_in[7];
  const float* Wr      = (const float*)d_in[8];
  const float* Wk      = (const float*)d_in[9];
  const float* Wv      = (const float*)d_in[10];
  const float* Wo      = (const float*)d_in[11];
  const float* w_decay = (const float*)d_in[12];
  const float* g_v     = (const float*)d_in[13];
  const float* Wb      = (const float*)d_in[14];
  const float* bb      = (const float*)d_in[15];
  const float* Wk_r    = (const float*)d_in[16];
  const float* Wv_r    = (const float*)d_in[17];
  const float* Wr_r    = (const float*)d_in[18];
  const float* W1_t    = (const float*)d_in[19];
  const float* W2_t    = (const float*)d_in[20];
  float* out = (float*)d_out;

  char* p = (char*)d_ws;
  auto alloc = [&](size_t bytes)->char*{ char* r=p; p += (bytes+255)&~(size_t)255; return r; };
  u16* wTrkv = (u16*)alloc(3072ull*1024*2);
  u16* wTo   = (u16*)alloc(1024ull*1024*2);
  u16* wTb   = (u16*)alloc(1024ull*2048*2);
  u16* wTkr  = (u16*)alloc(6ull*4096*1024*2);
  u16* wTvr  = (u16*)alloc(6ull*1024*4096*2);
  u16* wTrr  = (u16*)alloc(6ull*1024*1024*2);
  u16* wT1   = (u16*)alloc(2ull*4096*1024*2);
  u16* wT2   = (u16*)alloc(2ull*1024*4096*2);
  u16* h1    = (u16*)alloc(4096ull*1024*2);
  u16* rbuf  = (u16*)alloc(4096ull*1024*2);
  u16* kbuf  = (u16*)alloc(4096ull*1024*2);
  u16* vbuf  = (u16*)alloc(4096ull*1024*2);
  u16* rsb   = (u16*)alloc(4096ull*1024*2);
  u16* hcat  = (u16*)alloc(4096ull*2048*2);
  u16* htb   = (u16*)alloc(4096ull*1024*2);
  u16* act   = (u16*)alloc(8192ull*4096*2);
  u16* partial = (u16*)alloc(4ull*8192*1024*2);
  float* carry  = (float*)alloc(2ull*32*1024*4);
  float* startv = (float*)alloc(2ull*32*1024*4);
  int* offs   = (int*)alloc(16*4);
  int* cursor = (int*)alloc(8*4);
  int* idx_all= (int*)alloc(8192*4);

  dim3 B256(256);

  auto pad = [](CJobs& cj, int ji){ for (; ji<27; ++ji) cj.j[ji] = CJob{nullptr,nullptr,0,0,0x7FFFFFFF}; };

  // ---- conv small (weights needed by the pre-expert chain) ----
  CJobs cjS; int baseS = 0;
  {
    int ji = 0;
    auto add = [&](const float* s, u16* d, int K, int N){
      cjS.j[ji++] = CJob{s, d, K, N, baseS}; baseS += (K>>7)*(N>>6);
    };
    add(Wr, wTrkv, 1024,1024); add(Wk, wTrkv+1024*1024, 1024,1024);
    add(Wv, wTrkv+2048*1024, 1024,1024); add(Wo, wTo, 1024,1024);
    add(Wb, wTb, 2048,1024);
    pad(cjS, ji);
  }
  conv_all<<<dim3(baseS,1,1),B256,0,stream>>>(cjS);

  // ---- expert conv jobs, hosted in scan1 (E1) and scan3 (E2) ----
  CJobs cjE1; int baseE1 = 0;
  {
    int ji = 0;
    auto add = [&](const float* s, u16* d, int K, int N){
      cjE1.j[ji++] = CJob{s, d, K, N, baseE1}; baseE1 += (K>>7)*(N>>6);
    };
    for (int e2=0;e2<6;++e2) add(Wk_r + (size_t)e2*1024*4096, wTkr + (size_t)e2*4096*1024, 1024,4096);
    for (int e2=0;e2<6;++e2) add(Wr_r + (size_t)e2*1024*1024, wTrr + (size_t)e2*1024*1024, 1024,1024);
    pad(cjE1, ji);
  }
  CJobs cjE2; int baseE2 = 0;
  {
    int ji = 0;
    auto add = [&](const float* s, u16* d, int K, int N){
      cjE2.j[ji++] = CJob{s, d, K, N, baseE2}; baseE2 += (K>>7)*(N>>6);
    };
    for (int e2=0;e2<6;++e2) add(Wv_r + (size_t)e2*4096*1024, wTvr + (size_t)e2*1024*4096, 4096,1024);
    for (int e2=0;e2<2;++e2) add(W1_t + (size_t)e2*1024*4096, wT1 + (size_t)e2*4096*1024, 1024,4096);
    for (int e2=0;e2<2;++e2) add(W2_t + (size_t)e2*4096*1024, wT2 + (size_t)e2*1024*4096, 4096,1024);
    pad(cjE2, ji);
  }

  // routing
  route_count<<<1,B256,0,stream>>>(winners, offs, cursor);
  route_scatter<<<32,B256,0,stream>>>(winners, offs, cursor, idx_all);

  // LN1 -> h1
  ln_k<<<4096,B256,0,stream>>>(x, ln1_g, ln1_b, h1, 1024);

  // r|k|v = h1 @ [Wr|Wk|Wv]
  {
    GArgs ga{}; ga.A=h1; ga.B=wTrkv; ga.lda=1024; ga.K=1024; ga.Mdense=4096; ga.nxt=24; ga.kdiv=1024;
    ga.v_first=v_first; ga.g_v=g_v; ga.rbuf=rbuf; ga.kbuf=kbuf; ga.vbuf=vbuf;
    gemm_k<0,0><<<dim3(24,32,1),B256,0,stream>>>(ga);
  }

  // scan p1 (+ expert conv E1), p2, p3 (+ expert conv E2)
  scan1_conv<<<dim3(256+baseE1,1,1),B256,0,stream>>>(kbuf, vbuf, w_decay, carry, cjE1);
  scan_p2<<<dim3(4,2,1), B256,0,stream>>>(w_decay, carry, startv);
  scan3_conv<<<dim3(256+baseE2,1,1),B256,0,stream>>>(kbuf, vbuf, rbuf, w_decay, startv, rsb, hcat, cjE2);

  // attout partials (split-K 2) + fused reduce+LN2: out = x+attout, hcat[:, :1024] = LN(out)
  {
    GArgs ga{}; ga.A=rsb; ga.B=wTo; ga.lda=1024; ga.K=1024; ga.Mdense=4096; ga.nxt=8; ga.kdiv=512;
    ga.part=partial;
    gemm_k<1,0><<<dim3(16,32,1),B256,0,stream>>>(ga);
  }
  red_x_ln<<<4096,B256,0,stream>>>(x, partial, ln2_g, ln2_b, out, hcat);

  // bridge partials (split-K 2) + reduce: ht = h + bridge + bb
  {
    GArgs ga{}; ga.A=hcat; ga.B=wTb; ga.lda=2048; ga.K=2048; ga.Mdense=4096; ga.nxt=8; ga.kdiv=1024;
    ga.part=partial;
    gemm_k<2,0><<<dim3(16,32,1),B256,0,stream>>>(ga);
  }
  red_ht<<<4096,B256,0,stream>>>(hcat, partial, bb, htb);

  // merged expert phase A: relu^2(hcat@Wk_r) x6 | gelu(htb@W1) x2 | rec partials x6   (y=8 balanced)
  {
    MoeArgs ma{};
    ma.hcat=hcat; ma.htb=htb; ma.act=act;
    ma.wTkr=wTkr; ma.wT1=wT1; ma.wTrr=wTrr; ma.wTvr=wTvr; ma.wT2=wT2;
    ma.offs=offs; ma.idx_all=idx_all; ma.actw=act; ma.part=partial;
    gemm_moe<0><<<dim3(32,8,14),B256,0,stream>>>(ma);
    // merged expert phase B: (act@Wv_r) x6 split2 | (act@W2) x2 split4   (y=8 balanced)
    gemm_moe<1><<<dim3(32,8,8),B256,0,stream>>>(ma);
  }
  // combine experts into out
  red_moe<<<8192,B256,0,stream>>>(offs, idx_all, partial, out);

  (void)in_sizes; (void)n_in; (void)out_size; (void)ws_size;
}

// Round 13
// 703.296 us; speedup vs baseline: 1.0651x; 1.0050x over previous
//
#include <hip/hip_runtime.h>

typedef unsigned short u16;
typedef __bf16 bf16x8 __attribute__((ext_vector_type(8)));
typedef float f32x4 __attribute__((ext_vector_type(4)));

__device__ __forceinline__ float bf2f(u16 u){ union{unsigned i;float f;}x; x.i=((unsigned)u)<<16; return x.f; }
__device__ __forceinline__ u16 f2bf(float f){ union{float f;unsigned i;}x; x.f=f; unsigned r = x.i + 0x7FFFu + ((x.i>>16)&1u); return (u16)(r>>16); }
__device__ __forceinline__ float sigm(float x){ return 1.f/(1.f+expf(-x)); }

struct __align__(8) U16x4 { u16 v[4]; };

#define PSTRIDE 8388608ull   // elems per split in partial buffer [4][8192][1024]

// ---------------- f32 [K][N] -> bf16 [N][K] transpose-convert (shared tile body) ----------------
struct CJob { const float* src; u16* dst; int K, N, base; };
struct CJobs { CJob j[27]; };

__device__ __forceinline__ void conv_tile(const CJobs& cj, int id, u16 (*tile)[65]){
  int sel = 0;
  #pragma unroll
  for (int i=1;i<27;++i) if (cj.j[i].base <= id) sel = i;
  const float* __restrict__ src = cj.j[sel].src;
  u16* __restrict__ dst = cj.j[sel].dst;
  int K = cj.j[sel].K, N = cj.j[sel].N;
  int lt = id - cj.j[sel].base;
  int tn = N >> 6;
  int k0 = (lt / tn) * 128, n0 = (lt % tn) * 64;
  int tid = threadIdx.x;
  #pragma unroll
  for (int it=0; it<8; ++it){
    int e = it*1024 + tid*4;
    int r = e>>6, c = e&63;
    float4 v = *(const float4*)(src + (size_t)(k0+r)*N + n0 + c);
    tile[r][c+0]=f2bf(v.x); tile[r][c+1]=f2bf(v.y); tile[r][c+2]=f2bf(v.z); tile[r][c+3]=f2bf(v.w);
  }
  __syncthreads();
  #pragma unroll
  for (int it=0; it<8; ++it){
    int e = it*1024 + tid*4;
    int n = e>>7, k = e&127;
    U16x4 o;
    #pragma unroll
    for (int j=0;j<4;++j) o.v[j] = tile[k+j][n];
    *(U16x4*)(dst + (size_t)(n0+n)*K + k0 + k) = o;
  }
}

__global__ void conv_all(CJobs cj){
  __shared__ u16 tile[128][65];
  conv_tile(cj, blockIdx.x, tile);
}

// ---------------- LayerNorm: f32 [4096][1024] -> bf16 rows (stride ostride) ----------------
__global__ void ln_k(const float* __restrict__ x, const float* __restrict__ g, const float* __restrict__ b,
                     u16* __restrict__ out, int ostride){
  int row = blockIdx.x, tid = threadIdx.x;
  float4 v = *(const float4*)(x + (size_t)row*1024 + tid*4);
  float s = v.x+v.y+v.z+v.w;
  float ss = v.x*v.x+v.y*v.y+v.z*v.z+v.w*v.w;
  #pragma unroll
  for (int o=32;o;o>>=1){ s += __shfl_down(s,o); ss += __shfl_down(ss,o); }
  __shared__ float sm[8];
  int lane = tid&63, wv = tid>>6;
  if (!lane){ sm[wv]=s; sm[4+wv]=ss; }
  __syncthreads();
  s = sm[0]+sm[1]+sm[2]+sm[3]; ss = sm[4]+sm[5]+sm[6]+sm[7];
  float mean = s*(1.f/1024.f);
  float var = ss*(1.f/1024.f) - mean*mean;
  float inv = rsqrtf(var + 1e-5f);
  U16x4 o;
  const float* vp = &v.x;
  #pragma unroll
  for (int j=0;j<4;++j){
    int c = tid*4+j;
    o.v[j] = f2bf((vp[j]-mean)*inv*g[c] + b[c]);
  }
  *(U16x4*)(out + (size_t)row*ostride + tid*4) = o;
}

// ---------------- fused: out = x + p0 + p1 ; hcat[:, :1024] = LN(out) ----------------
__global__ void red_x_ln(const float* __restrict__ x, const u16* __restrict__ part,
                         const float* __restrict__ g, const float* __restrict__ b,
                         float* __restrict__ out, u16* __restrict__ hcat){
  int row = blockIdx.x, tid = threadIdx.x;
  size_t i = (size_t)row*1024 + tid*4;
  U16x4 p0 = *(const U16x4*)(part + i);
  U16x4 p1 = *(const U16x4*)(part + PSTRIDE + i);
  float4 xv = *(const float4*)(x + i);
  float4 v;
  v.x = xv.x + bf2f(p0.v[0]) + bf2f(p1.v[0]);
  v.y = xv.y + bf2f(p0.v[1]) + bf2f(p1.v[1]);
  v.z = xv.z + bf2f(p0.v[2]) + bf2f(p1.v[2]);
  v.w = xv.w + bf2f(p0.v[3]) + bf2f(p1.v[3]);
  *(float4*)(out + i) = v;
  float s = v.x+v.y+v.z+v.w;
  float ss = v.x*v.x+v.y*v.y+v.z*v.z+v.w*v.w;
  #pragma unroll
  for (int o=32;o;o>>=1){ s += __shfl_down(s,o); ss += __shfl_down(ss,o); }
  __shared__ float sm[8];
  int lane = tid&63, wv = tid>>6;
  if (!lane){ sm[wv]=s; sm[4+wv]=ss; }
  __syncthreads();
  s = sm[0]+sm[1]+sm[2]+sm[3]; ss = sm[4]+sm[5]+sm[6]+sm[7];
  float mean = s*(1.f/1024.f);
  float var = ss*(1.f/1024.f) - mean*mean;
  float inv = rsqrtf(var + 1e-5f);
  U16x4 o;
  const float* vp = &v.x;
  #pragma unroll
  for (int j=0;j<4;++j){
    int c = tid*4+j;
    o.v[j] = f2bf((vp[j]-mean)*inv*g[c] + b[c]);
  }
  *(U16x4*)(hcat + (size_t)row*2048 + tid*4) = o;
}

// ---------------- 3-phase chunked linear scan (p1 & p3 host expert-weight conv) ----------------
__global__ void scan1_conv(const u16* __restrict__ kbuf, const u16* __restrict__ vbuf,
                           const float* __restrict__ w_decay, float* __restrict__ carry, CJobs cj){
  __shared__ u16 tile[128][65];
  int id = blockIdx.x;
  if (id < 256){
    int c = (id&3)*256 + threadIdx.x;
    int chunk = (id>>2)&31, b = id>>7;
    float w = sigm(w_decay[c]);
    float s = 0.f;
    size_t idx = ((size_t)(b*2048 + chunk*64))*1024 + c;
    #pragma unroll 4
    for (int i=0;i<64;++i){ s = w*s + bf2f(kbuf[idx])*bf2f(vbuf[idx]); idx += 1024; }
    carry[((size_t)(b*32+chunk))*1024 + c] = s;
    return;
  }
  conv_tile(cj, id - 256, tile);
}
__global__ void scan_p2(const float* __restrict__ w_decay, const float* __restrict__ carry,
                        float* __restrict__ startv){
  int c = blockIdx.x*256 + threadIdx.x;
  int b = blockIdx.y;
  float w = sigm(w_decay[c]);
  float wL = w;
  #pragma unroll
  for (int i=0;i<6;++i) wL *= wL;   // w^64
  float p = 0.f;
  for (int j=0;j<32;++j){
    size_t id = ((size_t)(b*32+j))*1024 + c;
    startv[id] = p;
    p = wL*p + carry[id];
  }
}
__global__ void scan3_conv(const u16* __restrict__ kbuf, const u16* __restrict__ vbuf, const u16* __restrict__ rbuf,
                           const float* __restrict__ w_decay, const float* __restrict__ startv,
                           u16* __restrict__ rs, u16* __restrict__ hcat, CJobs cj){
  __shared__ u16 tile[128][65];
  int id = blockIdx.x;
  if (id < 256){
    int c = (id&3)*256 + threadIdx.x;
    int chunk = (id>>2)&31, b = id>>7;
    float w = sigm(w_decay[c]);
    float s = startv[((size_t)(b*32+chunk))*1024 + c];
    size_t t0 = (size_t)b*2048 + chunk*64;
    size_t idx = t0*1024 + c;
    size_t idx2 = t0*2048 + 1024 + c;
    for (int i=0;i<64;++i){
      s = w*s + bf2f(kbuf[idx])*bf2f(vbuf[idx]);
      rs[idx] = f2bf(bf2f(rbuf[idx]) * s);
      hcat[idx2] = f2bf(s);
      idx += 1024; idx2 += 2048;
    }
    return;
  }
  conv_tile(cj, id - 256, tile);
}

// ---------------- routing ----------------
__global__ void route_count(const int* __restrict__ winners, int* __restrict__ offs, int* __restrict__ cursor){
  __shared__ int cnt[8];
  if (threadIdx.x < 8) cnt[threadIdx.x] = 0;
  __syncthreads();
  for (int p = threadIdx.x; p < 8192; p += 256) atomicAdd(&cnt[winners[p]&7], 1);
  __syncthreads();
  if (threadIdx.x == 0){
    int s = 0;
    #pragma unroll
    for (int e=0;e<8;++e){ offs[e]=s; s+=cnt[e]; }
    offs[8]=s;
  }
  if (threadIdx.x < 8) cursor[threadIdx.x] = 0;
}
__global__ void route_scatter(const int* __restrict__ winners, const int* __restrict__ offs,
                              int* __restrict__ cursor, int* __restrict__ idx_all){
  int p = blockIdx.x*256 + threadIdx.x;
  if (p < 8192){
    int e = winners[p]&7;
    int pos = offs[e] + atomicAdd(&cursor[e], 1);
    idx_all[pos] = p>>1;
  }
}

// LDS slot swizzle (both-sides XOR, GLL dest stays linear):
//   writer lane l sources global slot ((l&3)^((l>>3)&3)); reader uses slot ((lane>>4)^((lane>>1)&3)).
// Ring-2 schedule (R12->R13): 2 LDS buffers (32KB), counted vmcnt(4) drains exactly the
// current buffer's 4 GLLs while next's 4 stay in flight; cadence identical to green ring-3.

// ---------------- universal 128x128 bf16 MFMA GEMM: BK=32, ring-2, depth-1 prefetch ----------------
struct GArgs {
  const u16* A; const u16* B;
  long long lda, bstride;
  int K, Mdense, eBase, nxt, kdiv;
  const int* offs; const int* idx_all;
  const float* v_first; const float* g_v;
  u16* rbuf; u16* kbuf; u16* vbuf;
  u16* act; u16* part;
};

#define GLL(gp, lp) __builtin_amdgcn_global_load_lds((const __attribute__((address_space(1))) void*)(gp), \
                                                     (__attribute__((address_space(3))) void*)(lp), 16, 0, 0)

template<int EPI, int GATHER>
__global__ __launch_bounds__(256,4) void gemm_k(GArgs g){
  int e = g.eBase + blockIdx.z;
  int rbase = 0, m = g.Mdense;
  if (g.offs){ rbase = g.offs[e]; m = g.offs[e+1] - rbase; }
  if ((int)blockIdx.y * 128 >= m) return;
  const int xt = (int)blockIdx.x % g.nxt;
  const int ksplit = (int)blockIdx.x / g.nxt;
  const long long kOff = (long long)ksplit * g.kdiv;
  __shared__ char smem[32768];          // 2 bufs x (A[128][32] 8KB + B[128][32] 8KB)
  const int tid = threadIdx.x, lane = tid&63, wave = tid>>6;
  const int wr = wave>>1, wc = wave&1;
  const int nk = g.kdiv >> 5;

  const int srowi = tid>>2;             // 0..63
  const long long scol = (long long)((((tid&3) ^ ((tid>>3)&3)))*8);   // pre-swizzled source slot

  const u16* bBase0 = g.B + (long long)blockIdx.z*g.bstride
                    + ((long long)(xt*128) + srowi)*(long long)g.K + kOff + scol;
  const u16* bBase1 = bBase0 + 64ll*(long long)g.K;

  const int sw = ((lane>>4) ^ ((lane>>1)&3)) << 4;                    // swizzled read slot (bytes)
  int aRd[4], bRd[4];
  #pragma unroll
  for (int q=0;q<4;++q){
    aRd[q] = (wr*64 + q*16 + (lane&15))*64 + sw;
    bRd[q] = 8192 + (wc*64 + q*16 + (lane&15))*64 + sw;
  }

  for (int mt = blockIdx.y; mt*128 < m; mt += gridDim.y){
    const u16 *aP0, *aP1;
    {
      int g0 = mt*128 + srowi;       g0 = g0 < m ? g0 : m-1;
      int g1 = mt*128 + 64 + srowi;  g1 = g1 < m ? g1 : m-1;
      long long r0, r1;
      if (GATHER){ r0 = g.idx_all[rbase+g0]; r1 = g.idx_all[rbase+g1]; }
      else if (g.offs){ r0 = rbase+g0; r1 = rbase+g1; }
      else { r0 = g0; r1 = g1; }
      aP0 = g.A + r0*g.lda + kOff + scol;
      aP1 = g.A + r1*g.lda + kOff + scol;
    }
    const u16* bP0 = bBase0;
    const u16* bP1 = bBase1;

    f32x4 acc[4][4];
    #pragma unroll
    for (int mm=0;mm<4;++mm)
      #pragma unroll
      for (int nn=0;nn<4;++nn)
        acc[mm][nn] = f32x4{0.f,0.f,0.f,0.f};

    #define STAGE(BUF) do{ \
      char* db = smem + (BUF)*16384 + wave*1024; \
      GLL(aP0, db); GLL(aP1, db+4096); GLL(bP0, db+8192); GLL(bP1, db+12288); \
      aP0+=32; aP1+=32; bP0+=32; bP1+=32; }while(0)

    STAGE(0);
    int cur = 0;
    for (int ks=0; ks<nk; ++ks){
      if (ks+1 < nk){
        STAGE(cur^1);
        asm volatile("s_waitcnt vmcnt(4)" ::: "memory");
      } else {
        asm volatile("s_waitcnt vmcnt(0)" ::: "memory");
      }
      asm volatile("s_barrier" ::: "memory");
      const char* base = smem + cur*16384;
      bf16x8 af[4], bfv[4];
      #pragma unroll
      for (int q=0;q<4;++q) af[q] = *(const bf16x8*)(base + aRd[q]);
      #pragma unroll
      for (int q=0;q<4;++q) bfv[q] = *(const bf16x8*)(base + bRd[q]);
      #pragma unroll
      for (int mm=0;mm<4;++mm)
        #pragma unroll
        for (int nn=0;nn<4;++nn)
          acc[mm][nn] = __builtin_amdgcn_mfma_f32_16x16x32_bf16(af[mm], bfv[nn], acc[mm][nn], 0,0,0);
      asm volatile("s_waitcnt lgkmcnt(0)" ::: "memory");
      asm volatile("s_barrier" ::: "memory");
      cur ^= 1;
    }
    #undef STAGE

    // epilogue
    int colB = xt*128 + wc*64 + (lane&15);
    #pragma unroll
    for (int mm=0;mm<4;++mm){
      #pragma unroll
      for (int j=0;j<4;++j){
        int grow = mt*128 + wr*64 + mm*16 + (lane>>4)*4 + j;
        if (grow >= m) continue;
        size_t gr = (size_t)(rbase + grow);
        #pragma unroll
        for (int nn=0;nn<4;++nn){
          int col = colB + nn*16;
          float val = acc[mm][nn][j];
          if (EPI==0){                                   // rkv split (dense: gr == token row)
            if (col < 1024) g.rbuf[gr*1024+col] = f2bf(sigm(val));
            else if (col < 2048) g.kbuf[gr*1024+col-1024] = f2bf(val);
            else {
              int c2 = col-2048;
              float sg = sigm(g.g_v[c2]);
              float vf = g.v_first[gr*1024+c2];
              g.vbuf[gr*1024+c2] = f2bf(val + (vf-val)*sg);
            }
          } else {                                       // partial write (EPI 1,2)
            g.part[(size_t)ksplit*PSTRIDE + gr*1024 + col] = f2bf(val);
          }
        }
      }
    }
  }
}

// ---------------- merged expert GEMMs (two phases, z-demux, XCD-chunked remap) ----------------
struct MoeArgs {
  const u16* hcat; const u16* htb; const u16* act;
  const u16* wTkr; const u16* wT1; const u16* wTrr; const u16* wTvr; const u16* wT2;
  const int* offs; const int* idx_all;
  u16* actw; u16* part;
};

template<int PHASE>
__global__ __launch_bounds__(256,4) void gemm_moe(MoeArgs g){
  // bijective XCD-chunked remap (T divisible by 8)
  const int T  = (int)(gridDim.x*gridDim.y*gridDim.z);
  const int id = (int)(blockIdx.x + gridDim.x*(blockIdx.y + gridDim.y*blockIdx.z));
  const int work = (id&7)*(T>>3) + (id>>3);
  const int bx = work % (int)gridDim.x;
  const int rest = work / (int)gridDim.x;
  const int by = rest % (int)gridDim.y;
  const int z  = rest / (int)gridDim.y;

  const u16 *Ap, *Bp; long long lda; int K, kdiv, nxt, e, epi;
  if (PHASE==0){
    if (z < 6){ e=z;   Ap=g.hcat; lda=2048; Bp=g.wTkr + (long long)z*4096*1024;     K=1024; kdiv=1024; nxt=32; epi=0; }
    else if (z < 8){ e=z; Ap=g.htb; lda=1024; Bp=g.wT1 + (long long)(z-6)*4096*1024; K=1024; kdiv=1024; nxt=32; epi=1; }
    else { e=z-8; Ap=g.hcat; lda=2048; Bp=g.wTrr + (long long)(z-8)*1024*1024;      K=1024; kdiv=512;  nxt=8;  epi=2; }
  } else {
    if (z < 6){ e=z; Ap=g.act; lda=4096; Bp=g.wTvr + (long long)z*1024*4096;        K=4096; kdiv=2048; nxt=8;  epi=3; }
    else { e=z;     Ap=g.act; lda=4096; Bp=g.wT2 + (long long)(z-6)*1024*4096;      K=4096; kdiv=1024; nxt=8;  epi=4; }
  }
  if (bx >= nxt * (K / kdiv)) return;
  int rbase = g.offs[e], m = g.offs[e+1] - rbase;
  if (by * 128 >= m) return;
  const int xt = bx % nxt;
  const int ksplit = bx / nxt;
  const long long kOff = (long long)ksplit * kdiv;
  __shared__ char smem[32768];
  const int tid = threadIdx.x, lane = tid&63, wave = tid>>6;
  const int wr = wave>>1, wc = wave&1;
  const int nk = kdiv >> 5;

  const int srowi = tid>>2;
  const long long scol = (long long)((((tid&3) ^ ((tid>>3)&3)))*8);

  const u16* bBase0 = Bp + ((long long)(xt*128) + srowi)*(long long)K + kOff + scol;
  const u16* bBase1 = bBase0 + 64ll*(long long)K;

  const int sw = ((lane>>4) ^ ((lane>>1)&3)) << 4;
  int aRd[4], bRd[4];
  #pragma unroll
  for (int q=0;q<4;++q){
    aRd[q] = (wr*64 + q*16 + (lane&15))*64 + sw;
    bRd[q] = 8192 + (wc*64 + q*16 + (lane&15))*64 + sw;
  }

  for (int mt = by; mt*128 < m; mt += gridDim.y){
    const u16 *aP0, *aP1;
    {
      int g0 = mt*128 + srowi;       g0 = g0 < m ? g0 : m-1;
      int g1 = mt*128 + 64 + srowi;  g1 = g1 < m ? g1 : m-1;
      long long r0, r1;
      if (epi <= 2){ r0 = g.idx_all[rbase+g0]; r1 = g.idx_all[rbase+g1]; }
      else { r0 = rbase+g0; r1 = rbase+g1; }
      aP0 = Ap + r0*lda + kOff + scol;
      aP1 = Ap + r1*lda + kOff + scol;
    }
    const u16* bP0 = bBase0;
    const u16* bP1 = bBase1;

    f32x4 acc[4][4];
    #pragma unroll
    for (int mm=0;mm<4;++mm)
      #pragma unroll
      for (int nn=0;nn<4;++nn)
        acc[mm][nn] = f32x4{0.f,0.f,0.f,0.f};

    #define STAGE(BUF) do{ \
      char* db = smem + (BUF)*16384 + wave*1024; \
      GLL(aP0, db); GLL(aP1, db+4096); GLL(bP0, db+8192); GLL(bP1, db+12288); \
      aP0+=32; aP1+=32; bP0+=32; bP1+=32; }while(0)

    STAGE(0);
    int cur = 0;
    for (int ks=0; ks<nk; ++ks){
      if (ks+1 < nk){
        STAGE(cur^1);
        asm volatile("s_waitcnt vmcnt(4)" ::: "memory");
      } else {
        asm volatile("s_waitcnt vmcnt(0)" ::: "memory");
      }
      asm volatile("s_barrier" ::: "memory");
      const char* base = smem + cur*16384;
      bf16x8 af[4], bfv[4];
      #pragma unroll
      for (int q=0;q<4;++q) af[q] = *(const bf16x8*)(base + aRd[q]);
      #pragma unroll
      for (int q=0;q<4;++q) bfv[q] = *(const bf16x8*)(base + bRd[q]);
      #pragma unroll
      for (int mm=0;mm<4;++mm)
        #pragma unroll
        for (int nn=0;nn<4;++nn)
          acc[mm][nn] = __builtin_amdgcn_mfma_f32_16x16x32_bf16(af[mm], bfv[nn], acc[mm][nn], 0,0,0);
      asm volatile("s_waitcnt lgkmcnt(0)" ::: "memory");
      asm volatile("s_barrier" ::: "memory");
      cur ^= 1;
    }
    #undef STAGE

    int colB = xt*128 + wc*64 + (lane&15);
    #pragma unroll
    for (int mm=0;mm<4;++mm){
      #pragma unroll
      for (int j=0;j<4;++j){
        int grow = mt*128 + wr*64 + mm*16 + (lane>>4)*4 + j;
        if (grow >= m) continue;
        size_t gr = (size_t)(rbase + grow);
        #pragma unroll
        for (int nn=0;nn<4;++nn){
          int col = colB + nn*16;
          float val = acc[mm][nn][j];
          if (epi == 0){                        // relu^2 -> act
            float r_ = fmaxf(val, 0.f);
            g.actw[gr*4096+col] = f2bf(r_*r_);
          } else if (epi == 1){                 // gelu -> act
            float t3 = val*val*val;
            float th = tanhf(0.79788456080286535588f*(val + 0.044715f*t3));
            g.actw[gr*4096+col] = f2bf(0.5f*val*(1.f+th));
          } else if (epi == 2){                 // rec partials, slots 2,3
            g.part[(size_t)(2+ksplit)*PSTRIDE + gr*1024 + col] = f2bf(val);
          } else {                              // expert-out partials, slots 0..3
            g.part[(size_t)ksplit*PSTRIDE + gr*1024 + col] = f2bf(val);
          }
        }
      }
    }
  }
}

// ---------------- reduce kernels ----------------
__global__ void red_ht(const u16* __restrict__ hcat, const u16* __restrict__ part,
                       const float* __restrict__ bb, u16* __restrict__ ht){
  int c = threadIdx.x*4;
  size_t i = (size_t)blockIdx.x*1024 + c;
  U16x4 p0 = *(const U16x4*)(part + i);
  U16x4 p1 = *(const U16x4*)(part + PSTRIDE + i);
  U16x4 hv = *(const U16x4*)(hcat + (size_t)blockIdx.x*2048 + c);
  U16x4 o;
  #pragma unroll
  for (int j=0;j<4;++j) o.v[j] = f2bf(bf2f(hv.v[j]) + bf2f(p0.v[j]) + bf2f(p1.v[j]) + bb[c+j]);
  *(U16x4*)(ht + i) = o;
}
// experts combine: rwkv rows: 0.5*sigm(p2+p3)*(p0+p1); trans rows: 0.5*(p0+p1+p2+p3)
__global__ void red_moe(const int* __restrict__ offs, const int* __restrict__ idx_all,
                        const u16* __restrict__ part, float* __restrict__ out){
  int gr = blockIdx.x;
  if (gr >= offs[8]) return;
  int tok = idx_all[gr];
  bool isr = gr < offs[6];
  int c = threadIdx.x*4;
  size_t i = (size_t)gr*1024 + c;
  U16x4 p0 = *(const U16x4*)(part + i);
  U16x4 p1 = *(const U16x4*)(part + PSTRIDE + i);
  U16x4 p2 = *(const U16x4*)(part + 2*PSTRIDE + i);
  U16x4 p3 = *(const U16x4*)(part + 3*PSTRIDE + i);
  #pragma unroll
  for (int j=0;j<4;++j){
    float v;
    if (isr){
      float rc = sigm(bf2f(p2.v[j]) + bf2f(p3.v[j]));
      v = 0.5f*(bf2f(p0.v[j]) + bf2f(p1.v[j]))*rc;
    } else {
      v = 0.5f*(bf2f(p0.v[j]) + bf2f(p1.v[j]) + bf2f(p2.v[j]) + bf2f(p3.v[j]));
    }
    atomicAdd(&out[(size_t)tok*1024 + c + j], v);
  }
}

// ---------------- host launch ----------------
extern "C" void kernel_launch(void* const* d_in, const int* in_sizes, int n_in,
                              void* d_out, int out_size, void* d_ws, size_t ws_size,
                              hipStream_t stream) {
  const float* x       = (const float*)d_in[0];
  const float* v_first = (const float*)d_in[1];
  const int*   winners = (const int*)d_in[2];
  const float* ln1_g   = (const float*)d_in[4];
  const float* ln1_b   = (const float*)d_in[5];
  const float* ln2_g   = (const float*)d_in[6];
  const float* ln2_b   = (const float*)d_in[7];
  const float* Wr      = (const float*)d_in[8];
  const float* Wk      = (const float*)d_in[9];
  const float* Wv      = (const float*)d_in[10];
  const float* Wo      = (const float*)d_in[11];
  const float* w_decay = (const float*)d_in[12];
  const float* g_v     = (const float*)d_in[13];
  const float* Wb      = (const float*)d_in[14];
  const float* bb      = (const float*)d_in[15];
  const float* Wk_r    = (const float*)d_in[16];
  const float* Wv_r    = (const float*)d_in[17];
  const float* Wr_r    = (const float*)d_in[18];
  const float* W1_t    = (const float*)d_in[19];
  const float* W2_t    = (const float*)d_in[20];
  float* out = (float*)d_out;

  char* p = (char*)d_ws;
  auto alloc = [&](size_t bytes)->char*{ char* r=p; p += (bytes+255)&~(size_t)255; return r; };
  u16* wTrkv = (u16*)alloc(3072ull*1024*2);
  u16* wTo   = (u16*)alloc(1024ull*1024*2);
  u16* wTb   = (u16*)alloc(1024ull*2048*2);
  u16* wTkr  = (u16*)alloc(6ull*4096*1024*2);
  u16* wTvr  = (u16*)alloc(6ull*1024*4096*2);
  u16* wTrr  = (u16*)alloc(6ull*1024*1024*2);
  u16* wT1   = (u16*)alloc(2ull*4096*1024*2);
  u16* wT2   = (u16*)alloc(2ull*1024*4096*2);
  u16* h1    = (u16*)alloc(4096ull*1024*2);
  u16* rbuf  = (u16*)alloc(4096ull*1024*2);
  u16* kbuf  = (u16*)alloc(4096ull*1024*2);
  u16* vbuf  = (u16*)alloc(4096ull*1024*2);
  u16* rsb   = (u16*)alloc(4096ull*1024*2);
  u16* hcat  = (u16*)alloc(4096ull*2048*2);
  u16* htb   = (u16*)alloc(4096ull*1024*2);
  u16* act   = (u16*)alloc(8192ull*4096*2);
  u16* partial = (u16*)alloc(4ull*8192*1024*2);
  float* carry  = (float*)alloc(2ull*32*1024*4);
  float* startv = (float*)alloc(2ull*32*1024*4);
  int* offs   = (int*)alloc(16*4);
  int* cursor = (int*)alloc(8*4);
  int* idx_all= (int*)alloc(8192*4);

  dim3 B256(256);

  auto pad = [](CJobs& cj, int ji){ for (; ji<27; ++ji) cj.j[ji] = CJob{nullptr,nullptr,0,0,0x7FFFFFFF}; };

  // ---- conv small (weights needed by the pre-expert chain) ----
  CJobs cjS; int baseS = 0;
  {
    int ji = 0;
    auto add = [&](const float* s, u16* d, int K, int N){
      cjS.j[ji++] = CJob{s, d, K, N, baseS}; baseS += (K>>7)*(N>>6);
    };
    add(Wr, wTrkv, 1024,1024); add(Wk, wTrkv+1024*1024, 1024,1024);
    add(Wv, wTrkv+2048*1024, 1024,1024); add(Wo, wTo, 1024,1024);
    add(Wb, wTb, 2048,1024);
    pad(cjS, ji);
  }
  conv_all<<<dim3(baseS,1,1),B256,0,stream>>>(cjS);

  // ---- expert conv jobs, hosted in scan1 (E1) and scan3 (E2) ----
  CJobs cjE1; int baseE1 = 0;
  {
    int ji = 0;
    auto add = [&](const float* s, u16* d, int K, int N){
      cjE1.j[ji++] = CJob{s, d, K, N, baseE1}; baseE1 += (K>>7)*(N>>6);
    };
    for (int e2=0;e2<6;++e2) add(Wk_r + (size_t)e2*1024*4096, wTkr + (size_t)e2*4096*1024, 1024,4096);
    for (int e2=0;e2<6;++e2) add(Wr_r + (size_t)e2*1024*1024, wTrr + (size_t)e2*1024*1024, 1024,1024);
    pad(cjE1, ji);
  }
  CJobs cjE2; int baseE2 = 0;
  {
    int ji = 0;
    auto add = [&](const float* s, u16* d, int K, int N){
      cjE2.j[ji++] = CJob{s, d, K, N, baseE2}; baseE2 += (K>>7)*(N>>6);
    };
    for (int e2=0;e2<6;++e2) add(Wv_r + (size_t)e2*4096*1024, wTvr + (size_t)e2*1024*4096, 4096,1024);
    for (int e2=0;e2<2;++e2) add(W1_t + (size_t)e2*1024*4096, wT1 + (size_t)e2*4096*1024, 1024,4096);
    for (int e2=0;e2<2;++e2) add(W2_t + (size_t)e2*4096*1024, wT2 + (size_t)e2*1024*4096, 4096,1024);
    pad(cjE2, ji);
  }

  // routing
  route_count<<<1,B256,0,stream>>>(winners, offs, cursor);
  route_scatter<<<32,B256,0,stream>>>(winners, offs, cursor, idx_all);

  // LN1 -> h1
  ln_k<<<4096,B256,0,stream>>>(x, ln1_g, ln1_b, h1, 1024);

  // r|k|v = h1 @ [Wr|Wk|Wv]
  {
    GArgs ga{}; ga.A=h1; ga.B=wTrkv; ga.lda=1024; ga.K=1024; ga.Mdense=4096; ga.nxt=24; ga.kdiv=1024;
    ga.v_first=v_first; ga.g_v=g_v; ga.rbuf=rbuf; ga.kbuf=kbuf; ga.vbuf=vbuf;
    gemm_k<0,0><<<dim3(24,32,1),B256,0,stream>>>(ga);
  }

  // scan p1 (+ expert conv E1), p2, p3 (+ expert conv E2)
  scan1_conv<<<dim3(256+baseE1,1,1),B256,0,stream>>>(kbuf, vbuf, w_decay, carry, cjE1);
  scan_p2<<<dim3(4,2,1), B256,0,stream>>>(w_decay, carry, startv);
  scan3_conv<<<dim3(256+baseE2,1,1),B256,0,stream>>>(kbuf, vbuf, rbuf, w_decay, startv, rsb, hcat, cjE2);

  // attout partials (split-K 2) + fused reduce+LN2: out = x+attout, hcat[:, :1024] = LN(out)
  {
    GArgs ga{}; ga.A=rsb; ga.B=wTo; ga.lda=1024; ga.K=1024; ga.Mdense=4096; ga.nxt=8; ga.kdiv=512;
    ga.part=partial;
    gemm_k<1,0><<<dim3(16,32,1),B256,0,stream>>>(ga);
  }
  red_x_ln<<<4096,B256,0,stream>>>(x, partial, ln2_g, ln2_b, out, hcat);

  // bridge partials (split-K 2) + reduce: ht = h + bridge + bb
  {
    GArgs ga{}; ga.A=hcat; ga.B=wTb; ga.lda=2048; ga.K=2048; ga.Mdense=4096; ga.nxt=8; ga.kdiv=1024;
    ga.part=partial;
    gemm_k<2,0><<<dim3(16,32,1),B256,0,stream>>>(ga);
  }
  red_ht<<<4096,B256,0,stream>>>(hcat, partial, bb, htb);

  // merged expert phase A: relu^2(hcat@Wk_r) x6 | gelu(htb@W1) x2 | rec partials x6   (y=8 balanced)
  {
    MoeArgs ma{};
    ma.hcat=hcat; ma.htb=htb; ma.act=act;
    ma.wTkr=wTkr; ma.wT1=wT1; ma.wTrr=wTrr; ma.wTvr=wTvr; ma.wT2=wT2;
    ma.offs=offs; ma.idx_all=idx_all; ma.actw=act; ma.part=partial;
    gemm_moe<0><<<dim3(32,8,14),B256,0,stream>>>(ma);
    // merged expert phase B: (act@Wv_r) x6 split2 | (act@W2) x2 split4   (y=8 balanced)
    gemm_moe<1><<<dim3(32,8,8),B256,0,stream>>>(ma);
  }
  // combine experts into out
  red_moe<<<8192,B256,0,stream>>>(offs, idx_all, partial, out);

  (void)in_sizes; (void)n_in; (void)out_size; (void)ws_size;
}